// Round 2
// baseline (5749.259 us; speedup 1.0000x reference)
//
#include <hip/hip_runtime.h>
#include <hip/hip_bf16.h>

// Mamba2 block forward. B=4 L=4096 D_MODEL=512 D_INNER=2048 H=8 P=256 N=64
// CHUNK=256 C=16 CONV_DIM=2176.
// Round 2: workspace cut 622MB -> 233MiB (bf16 intermediates, fused SSD y,
// in-place scan). f32 accumulation everywhere.

#define BB 4
#define LL 4096
#define DM 512
#define DI 2048
#define NH 8
#define HD 256
#define DS 64
#define DCONV 4
#define CHK 256
#define NC 16
#define CONVD 2176
#define MROWS (BB*LL)   // 16384

typedef __hip_bfloat16 bf16;

__device__ __forceinline__ float ldf(const float* p) { return *p; }
__device__ __forceinline__ float ldf(const bf16* p) { return __bfloat162float(*p); }
__device__ __forceinline__ void stf(float* p, float v) { *p = v; }
__device__ __forceinline__ void stf(bf16* p, float v) { *p = __float2bfloat16(v); }

// ---------------- generic 64x64 tiled GEMM (f32 compute) ----------------
template <typename TA, typename TC>
__global__ void gemm_kernel(const TA* __restrict__ A, const float* __restrict__ B,
                            TC* __restrict__ C, int K, int lda, int ldb, int ldc) {
    __shared__ float As[16][64 + 1];
    __shared__ float Bs[16][64 + 1];
    const int tid = threadIdx.x;
    const long m0 = (long)blockIdx.y * 64, n0 = (long)blockIdx.x * 64;
    const int tx = tid & 15, ty = tid >> 4;
    float acc[4][4] = {};
    for (int k0 = 0; k0 < K; k0 += 16) {
#pragma unroll
        for (int i = 0; i < 4; i++) {
            int idx = tid + i * 256;
            int m = idx >> 4, k = idx & 15;
            As[k][m] = ldf(A + (m0 + m) * (long)lda + k0 + k);
        }
#pragma unroll
        for (int i = 0; i < 4; i++) {
            int idx = tid + i * 256;
            int k = idx >> 6, n = idx & 63;
            Bs[k][n] = B[(long)(k0 + k) * ldb + n0 + n];
        }
        __syncthreads();
#pragma unroll
        for (int k = 0; k < 16; k++) {
            float a[4], bb[4];
#pragma unroll
            for (int i = 0; i < 4; i++) a[i] = As[k][ty * 4 + i];
#pragma unroll
            for (int j = 0; j < 4; j++) bb[j] = Bs[k][tx * 4 + j];
#pragma unroll
            for (int i = 0; i < 4; i++)
#pragma unroll
                for (int j = 0; j < 4; j++) acc[i][j] += a[i] * bb[j];
        }
        __syncthreads();
    }
#pragma unroll
    for (int i = 0; i < 4; i++)
#pragma unroll
        for (int j = 0; j < 4; j++)
            stf(&C[(m0 + ty * 4 + i) * (long)ldc + n0 + tx * 4 + j], acc[i][j]);
}

// ---------------- dt = softplus(inputs @ Wdt + bias) ----------------
__global__ void dt_kernel(const float* __restrict__ inp, const float* __restrict__ Wdt,
                          const float* __restrict__ dt_bias, float* __restrict__ dtb) {
    int idx = blockIdx.x * 256 + threadIdx.x;  // MROWS*NH
    int h = idx & 7;
    long row = idx >> 3;
    const float* ir = inp + row * DM;
    float acc = 0.f;
    for (int k = 0; k < DM; k++) acc += ir[k] * Wdt[k * NH + h];
    acc += dt_bias[h];
    float sp = acc > 20.f ? acc : log1pf(expf(acc));
    dtb[idx] = sp;
}

// ---------------- conv(4) + silu + split + x*dt ----------------
__global__ void conv_silu_split(const bf16* __restrict__ xbc, const float* __restrict__ ck,
                                const float* __restrict__ dtb, bf16* __restrict__ xdt,
                                bf16* __restrict__ bm, bf16* __restrict__ cm) {
    long idx = (long)blockIdx.x * 256 + threadIdx.x;  // MROWS*CONVD
    if (idx >= (long)MROWS * CONVD) return;
    int ch = (int)(idx % CONVD);
    long bl = idx / CONVD;
    int l = (int)(bl % LL);
    float acc = 0.f;
#pragma unroll
    for (int k = 0; k < DCONV; k++) {
        int ls = l - 3 + k;
        if (ls >= 0) acc += ldf(&xbc[(bl - l + ls) * CONVD + ch]) * ck[k * CONVD + ch];
    }
    float s = acc / (1.f + expf(-acc));
    if (ch < DI) {
        int h = ch >> 8;
        stf(&xdt[bl * DI + ch], s * dtb[bl * NH + h]);
    } else if (ch < DI + DS) {
        stf(&bm[bl * DS + (ch - DI)], s);
    } else {
        stf(&cm[bl * DS + (ch - DI - DS)], s);
    }
}

// ---------------- per-(b,h,c) cumsum of a*dt ----------------
__global__ void cumsum_kernel(const float* __restrict__ dtb, const float* __restrict__ a_log,
                              float* __restrict__ cumA, float* __restrict__ csum) {
    int t = blockIdx.x * 256 + threadIdx.x;  // 512 = B*H*NC, t = b*128 + h*16 + c
    if (t >= BB * NH * NC) return;
    int c = t & 15, h = (t >> 4) & 7, b = t >> 7;
    float a = -expf(a_log[h]);
    long base_l = (long)b * LL + (long)c * CHK;
    float s = 0.f;
    long obase = (long)t * CHK;
    for (int i = 0; i < CHK; i++) {
        s += a * dtb[(base_l + i) * NH + h];
        cumA[obase + i] = s;
    }
    csum[t] = s;
}

// ---------------- states[p,n] = sum_l b[l,n]*exp(A - cumA_l)*x[l,p] ----------------
__global__ void states_kernel(const bf16* __restrict__ bmat, const bf16* __restrict__ xdt,
                              const float* __restrict__ cumA, const float* __restrict__ csum,
                              float* __restrict__ st) {
    int z = blockIdx.x;  // z = b*128 + c*8 + h
    int h = z & 7, c = (z >> 3) & 15, b = z >> 7;
    __shared__ float bs[256][64];
    __shared__ float dec[256];
    int tid = threadIdx.x;
    long blbase = (long)b * LL + (long)c * CHK;
    int bhc = (b * NH + h) * NC + c;
    float A = csum[bhc];
    dec[tid] = expf(A - cumA[(long)bhc * CHK + tid]);
    __syncthreads();
#pragma unroll
    for (int i = 0; i < 64; i++) {
        int idx = tid + i * 256;
        int l = idx >> 6, n = idx & 63;
        bs[l][n] = ldf(&bmat[blbase * DS + idx]) * dec[l];
    }
    __syncthreads();
    float acc[64] = {};
    const bf16* xb = xdt + (blbase * DI) + h * HD;
    for (int l = 0; l < 256; l++) {
        float xv = ldf(&xb[(long)l * DI + tid]);
#pragma unroll
        for (int n = 0; n < 64; n++) acc[n] += bs[l][n] * xv;
    }
    float* so = st + (long)z * (HD * DS) + tid * DS;
#pragma unroll
    for (int n = 0; n < 64; n++) so[n] = acc[n];
}

// ---------------- serial chunk scan (IN PLACE: st becomes states-before) ----------------
__global__ void scan_kernel(float* __restrict__ st, const float* __restrict__ csum) {
    long idx = (long)blockIdx.x * 256 + threadIdx.x;  // B*H*16384
    int pn = (int)(idx & 16383);
    int h = (int)((idx >> 14) & 7);
    int b = (int)(idx >> 17);
    float S = 0.f;
    for (int c = 0; c < NC; c++) {
        long si = (((long)(b * NC + c) * NH + h) * (HD * DS)) + pn;
        float chunk = st[si];
        st[si] = S;
        S = S * expf(csum[(b * NH + h) * NC + c]) + chunk;
    }
}

// ---------------- fused y = y_diag + y_off per (b,c,h) ----------------
// y[l,p] = sum_{s<=l} (c_l.b_s) exp(cumA_l - cumA_s) x[s,p]  +  exp(cumA_l) (c_l . S[p,:])
__global__ void ssd_y_kernel(const bf16* __restrict__ bmat, const bf16* __restrict__ cmat,
                             const bf16* __restrict__ xdt, const float* __restrict__ st,
                             const float* __restrict__ cumA, bf16* __restrict__ y) {
    int z = blockIdx.x;  // z = b*128 + c*8 + h
    int h = z & 7, c = (z >> 3) & 15, b = z >> 7;
    __shared__ bf16 x_lds[256][256];   // 128 KB
    __shared__ float wrow[256];
    __shared__ float cum_lds[256];
    __shared__ float c_cur[64];
    int tid = threadIdx.x;
    long blbase = (long)b * LL + (long)c * CHK;
    int bhc = (b * NH + h) * NC + c;

    // stage x tile (bf16), 8B vector copies, coalesced
    const bf16* xg = xdt + blbase * DI + h * HD;
#pragma unroll
    for (int i = 0; i < 64; i++) {
        int e = (tid + i * 256) * 4;
        int row = e >> 8, col = e & 255;
        *(uint2*)&x_lds[row][col] = *(const uint2*)&xg[(long)row * DI + col];
    }
    cum_lds[tid] = cumA[(long)bhc * CHK + tid];

    float breg[64];
    const bf16* bg = bmat + (blbase + tid) * DS;
#pragma unroll
    for (int n = 0; n < 64; n++) breg[n] = ldf(&bg[n]);
    float S[64];
    const float* sp = st + (long)z * (HD * DS) + tid * DS;
#pragma unroll
    for (int n = 0; n < 64; n++) S[n] = sp[n];
    __syncthreads();

    float cs = cum_lds[tid];
    bf16* yb = y + blbase * DI + h * HD;
    for (int l = 0; l < 256; l++) {
        if (tid < 64) c_cur[tid] = ldf(&cmat[(blbase + l) * DS + tid]);
        __syncthreads();
        float cl = cum_lds[l];
        float dotB = 0.f, dotS = 0.f;
#pragma unroll
        for (int n = 0; n < 64; n++) {
            float cv = c_cur[n];
            dotB += cv * breg[n];
            dotS += cv * S[n];
        }
        wrow[tid] = (tid <= l) ? dotB * expf(cl - cs) : 0.f;
        __syncthreads();
        float acc = expf(cl) * dotS;
        for (int s = 0; s <= l; s++) acc += wrow[s] * ldf(&x_lds[s][tid]);
        stf(&yb[(long)l * DI + tid], acc);
        __syncthreads();
    }
}

// ---------------- gate (silu(z)) + RMSNorm ----------------
__global__ void gatenorm_kernel(const bf16* __restrict__ y, const bf16* __restrict__ z,
                                const float* __restrict__ gamma, bf16* __restrict__ out) {
    int row = blockIdx.x;
    int tid = threadIdx.x;
    float g[8];
    float ss = 0.f;
#pragma unroll
    for (int i = 0; i < 8; i++) {
        int d = tid + i * 256;
        float yv = ldf(&y[(long)row * DI + d]);
        float zv = ldf(&z[(long)row * DI + d]);
        float gate = zv / (1.f + expf(-zv));
        float v = yv * gate;
        g[i] = v;
        ss += v * v;
    }
#pragma unroll
    for (int off = 32; off > 0; off >>= 1) ss += __shfl_down(ss, off);
    __shared__ float red[4];
    if ((tid & 63) == 0) red[tid >> 6] = ss;
    __syncthreads();
    float tot = red[0] + red[1] + red[2] + red[3];
    float scale = rsqrtf(tot / (float)DI + 1e-5f);
#pragma unroll
    for (int i = 0; i < 8; i++) {
        int d = tid + i * 256;
        stf(&out[(long)row * DI + d], g[i] * scale * gamma[d]);
    }
}

extern "C" void kernel_launch(void* const* d_in, const int* in_sizes, int n_in,
                              void* d_out, int out_size, void* d_ws, size_t ws_size,
                              hipStream_t stream) {
    const float* inputs = (const float*)d_in[0];
    const float* Wz = (const float*)d_in[1];
    const float* Wxbc = (const float*)d_in[2];
    const float* Wdt = (const float*)d_in[3];
    const float* conv_kernel = (const float*)d_in[4];
    const float* dt_bias = (const float*)d_in[5];
    const float* a_log = (const float*)d_in[6];
    const float* gamma = (const float*)d_in[7];
    const float* Wout = (const float*)d_in[8];
    float* out = (float*)d_out;

    // ---- workspace layout (233 MiB total) ----
    char* ws = (char*)d_ws;
    float* dtb = (float*)ws;                      ws += (long)MROWS * NH * 4;        // 0.5 MB
    float* cumA = (float*)ws;                     ws += (long)MROWS * NH * 4;        // 0.5 MB
    float* csum = (float*)ws;                     ws += 512 * 4;
    float* st = (float*)ws;                       ws += (long)BB * NC * NH * HD * DS * 4;  // 33.5 MB
    bf16* zb = (bf16*)ws;                         ws += (long)MROWS * DI * 2;        // 67 MB
    bf16* xbcy = (bf16*)ws;                       ws += (long)MROWS * CONVD * 2;     // 71 MB (xbc; later y)
    bf16* xdtn = (bf16*)ws;                       ws += (long)MROWS * DI * 2;        // 67 MB (x*dt; later ynorm)
    bf16* bmat = (bf16*)ws;                       ws += (long)MROWS * DS * 2;        // 2 MB
    bf16* cmat = (bf16*)ws;                       ws += (long)MROWS * DS * 2;        // 2 MB
    bf16* ybuf = xbcy;   // xbc dead after conv
    bf16* ynorm = xdtn;  // x*dt dead after ssd_y

    // 1. z = inputs @ Wz  (bf16 out)
    gemm_kernel<float, bf16><<<dim3(DI / 64, MROWS / 64), 256, 0, stream>>>(inputs, Wz, zb, DM, DM, DI, DI);
    // 2. xbc = inputs @ Wxbc  (bf16 out)
    gemm_kernel<float, bf16><<<dim3(CONVD / 64, MROWS / 64), 256, 0, stream>>>(inputs, Wxbc, xbcy, DM, DM, CONVD, CONVD);
    // 3. dt
    dt_kernel<<<MROWS * NH / 256, 256, 0, stream>>>(inputs, Wdt, dt_bias, dtb);
    // 4. conv + silu + split + x*dt
    long convtot = (long)MROWS * CONVD;
    conv_silu_split<<<(unsigned)((convtot + 255) / 256), 256, 0, stream>>>(xbcy, conv_kernel, dtb, xdtn, bmat, cmat);
    // 5. cumsum
    cumsum_kernel<<<2, 256, 0, stream>>>(dtb, a_log, cumA, csum);
    // 6. per-chunk states
    states_kernel<<<BB * NC * NH, 256, 0, stream>>>(bmat, xdtn, cumA, csum, st);
    // 7. chunk scan (in place)
    scan_kernel<<<BB * NH * HD * DS / 256, 256, 0, stream>>>(st, csum);
    // 8. fused y = y_diag + y_off  (writes ybuf, overwriting dead xbc region)
    ssd_y_kernel<<<BB * NC * NH, 256, 0, stream>>>(bmat, cmat, xdtn, st, cumA, ybuf);
    // 9. gate + rmsnorm (ynorm overwrites dead x*dt region)
    gatenorm_kernel<<<MROWS, 256, 0, stream>>>(ybuf, zb, gamma, ynorm);
    // 10. out = ynorm @ Wout
    gemm_kernel<bf16, float><<<dim3(DM / 64, MROWS / 64), 256, 0, stream>>>(ynorm, Wout, out, DI, DI, DM, DM);
}

// Round 3
// 751.573 us; speedup vs baseline: 7.6496x; 7.6496x over previous
//
#include <hip/hip_runtime.h>
#include <hip/hip_bf16.h>

// Mamba2 block forward. B=4 L=4096 D_MODEL=512 D_INNER=2048 H=8 P=256 N=64
// CHUNK=256 C=16 CONV_DIM=2176.
// Round 3: bf16 MFMA for dense GEMMs and the SSD core (W-gemm + Y-gemm,
// flash-attention-like). Workspace ~191 MiB. f32 accumulation everywhere.

#define BB 4
#define LL 4096
#define DM 512
#define DI 2048
#define NH 8
#define HD 256
#define DS 64
#define DCONV 4
#define CHK 256
#define NC 16
#define CONVD 2176
#define MROWS (BB*LL)   // 16384

typedef __hip_bfloat16 bf16;
typedef short s8 __attribute__((ext_vector_type(8)));   // 8 bf16 (4 VGPRs)
typedef float f4 __attribute__((ext_vector_type(4)));   // MFMA acc

__device__ __forceinline__ f4 mfma16(s8 a, s8 b, f4 c) {
    return __builtin_amdgcn_mfma_f32_16x16x32_bf16(a, b, c, 0, 0, 0);
}

__device__ __forceinline__ float ldf(const float* p) { return *p; }
__device__ __forceinline__ float ldf(const bf16* p) { return __bfloat162float(*p); }
__device__ __forceinline__ void stf(float* p, float v) { *p = v; }
__device__ __forceinline__ void stf(bf16* p, float v) { *p = __float2bfloat16(v); }

// ---------------- f32 -> bf16 cast (elementwise, 8/thread) ----------------
__global__ void cast_bf16_kernel(const float* __restrict__ in, bf16* __restrict__ out) {
    long i8 = ((long)blockIdx.x * 256 + threadIdx.x) * 8;
    float4 a = *(const float4*)&in[i8];
    float4 b = *(const float4*)&in[i8 + 4];
    bf16 v[8];
    v[0] = __float2bfloat16(a.x); v[1] = __float2bfloat16(a.y);
    v[2] = __float2bfloat16(a.z); v[3] = __float2bfloat16(a.w);
    v[4] = __float2bfloat16(b.x); v[5] = __float2bfloat16(b.y);
    v[6] = __float2bfloat16(b.z); v[7] = __float2bfloat16(b.w);
    *(uint4*)&out[i8] = *(uint4*)v;
}

// ---------------- f32 [K][N] -> bf16 [N][K] transpose-cast ----------------
__global__ void tcast_kernel(const float* __restrict__ in, bf16* __restrict__ out,
                             int K, int N) {
    __shared__ float tile[64][65];
    int t = threadIdx.x;
    int n0 = blockIdx.x * 64, k0 = blockIdx.y * 64;
#pragma unroll
    for (int i = 0; i < 16; i++) {
        int u = t + i * 256; int kr = u >> 6, nc = u & 63;
        tile[kr][nc] = in[(long)(k0 + kr) * N + n0 + nc];
    }
    __syncthreads();
#pragma unroll
    for (int i = 0; i < 16; i++) {
        int u = t + i * 256; int nr = u >> 6, kc = u & 63;
        out[(long)(n0 + nr) * K + k0 + kc] = __float2bfloat16(tile[kc][nr]);
    }
}

// ---------------- bf16 MFMA GEMM: C[M][N] = A[M][K] @ BT[N][K]^T ----------------
// 128x128 tile, BK=64, 4 waves (2x2 of 64x64), 16x16x32 MFMA.
template <typename TC>
__global__ __launch_bounds__(256) void mfma_gemm(const bf16* __restrict__ A,
                                                 const bf16* __restrict__ BT,
                                                 TC* __restrict__ C, int N, int K) {
    __shared__ __align__(16) bf16 At[128][72];
    __shared__ __align__(16) bf16 Bt[128][72];
    const int t = threadIdx.x, lane = t & 63, w = t >> 6;
    const int wr = w >> 1, wc = w & 1;
    const long m0 = (long)blockIdx.y * 128;
    const int n0 = blockIdx.x * 128;
    f4 acc[4][4];
#pragma unroll
    for (int mi = 0; mi < 4; mi++)
#pragma unroll
        for (int ni = 0; ni < 4; ni++) acc[mi][ni] = (f4){0.f, 0.f, 0.f, 0.f};

    for (int k0 = 0; k0 < K; k0 += 64) {
#pragma unroll
        for (int i = 0; i < 4; i++) {
            int u = t + i * 256; int m = u >> 3, k8 = (u & 7) * 8;
            *(uint4*)&At[m][k8] = *(const uint4*)&A[(m0 + m) * (long)K + k0 + k8];
            *(uint4*)&Bt[m][k8] = *(const uint4*)&BT[((long)n0 + m) * K + k0 + k8];
        }
        __syncthreads();
#pragma unroll
        for (int ks = 0; ks < 2; ks++) {
            s8 af[4], bfr[4];
#pragma unroll
            for (int mi = 0; mi < 4; mi++)
                af[mi] = *(const s8*)&At[wr * 64 + mi * 16 + (lane & 15)][ks * 32 + (lane >> 4) * 8];
#pragma unroll
            for (int ni = 0; ni < 4; ni++)
                bfr[ni] = *(const s8*)&Bt[wc * 64 + ni * 16 + (lane & 15)][ks * 32 + (lane >> 4) * 8];
#pragma unroll
            for (int mi = 0; mi < 4; mi++)
#pragma unroll
                for (int ni = 0; ni < 4; ni++)
                    acc[mi][ni] = mfma16(af[mi], bfr[ni], acc[mi][ni]);
        }
        __syncthreads();
    }
#pragma unroll
    for (int mi = 0; mi < 4; mi++)
#pragma unroll
        for (int ni = 0; ni < 4; ni++)
#pragma unroll
            for (int r = 0; r < 4; r++)
                stf(&C[(m0 + wr * 64 + mi * 16 + (lane >> 4) * 4 + r) * (long)N +
                       n0 + wc * 64 + ni * 16 + (lane & 15)], acc[mi][ni][r]);
}

// ---------------- dt = softplus(inputs @ Wdt + bias) ----------------
__global__ void dt_kernel(const float* __restrict__ inp, const float* __restrict__ Wdt,
                          const float* __restrict__ dt_bias, float* __restrict__ dtb) {
    int idx = blockIdx.x * 256 + threadIdx.x;
    int h = idx & 7;
    long row = idx >> 3;
    const float* ir = inp + row * DM;
    float acc = 0.f;
    for (int k = 0; k < DM; k++) acc += ir[k] * Wdt[k * NH + h];
    acc += dt_bias[h];
    float sp = acc > 20.f ? acc : log1pf(expf(acc));
    dtb[idx] = sp;
}

// ---------------- conv(4) + silu + split + x*dt ----------------
__global__ void conv_silu_split(const bf16* __restrict__ xbc, const float* __restrict__ ck,
                                const float* __restrict__ dtb, bf16* __restrict__ xdt,
                                bf16* __restrict__ bm, bf16* __restrict__ cm) {
    long idx = (long)blockIdx.x * 256 + threadIdx.x;
    if (idx >= (long)MROWS * CONVD) return;
    int ch = (int)(idx % CONVD);
    long bl = idx / CONVD;
    int l = (int)(bl % LL);
    float acc = 0.f;
#pragma unroll
    for (int k = 0; k < DCONV; k++) {
        int ls = l - 3 + k;
        if (ls >= 0) acc += ldf(&xbc[(bl - l + ls) * CONVD + ch]) * ck[k * CONVD + ch];
    }
    float s = acc / (1.f + expf(-acc));
    if (ch < DI) {
        int h = ch >> 8;
        stf(&xdt[bl * DI + ch], s * dtb[bl * NH + h]);
    } else if (ch < DI + DS) {
        stf(&bm[bl * DS + (ch - DI)], s);
    } else {
        stf(&cm[bl * DS + (ch - DI - DS)], s);
    }
}

// ---------------- per-(b,h,c) cumsum of a*dt ----------------
__global__ void cumsum_kernel(const float* __restrict__ dtb, const float* __restrict__ a_log,
                              float* __restrict__ cumA, float* __restrict__ csum) {
    int t = blockIdx.x * 256 + threadIdx.x;  // t = b*128 + h*16 + c
    if (t >= BB * NH * NC) return;
    int c = t & 15, h = (t >> 4) & 7, b = t >> 7;
    float a = -expf(a_log[h]);
    long base_l = (long)b * LL + (long)c * CHK;
    float s = 0.f;
    long obase = (long)t * CHK;
    for (int i = 0; i < CHK; i++) {
        s += a * dtb[(base_l + i) * NH + h];
        cumA[obase + i] = s;
    }
    csum[t] = s;
}

// ---------------- states[p,n] = sum_l b[l,n]*exp(A - cumA_l)*x[l,p] ----------------
__global__ void states_kernel(const bf16* __restrict__ bmat, const bf16* __restrict__ xdt,
                              const float* __restrict__ cumA, const float* __restrict__ csum,
                              float* __restrict__ st) {
    int z = blockIdx.x;  // z = b*128 + c*8 + h
    int h = z & 7, c = (z >> 3) & 15, b = z >> 7;
    __shared__ float bs[256][64];
    __shared__ float dec[256];
    int tid = threadIdx.x;
    long blbase = (long)b * LL + (long)c * CHK;
    int bhc = (b * NH + h) * NC + c;
    float A = csum[bhc];
    dec[tid] = expf(A - cumA[(long)bhc * CHK + tid]);
    __syncthreads();
#pragma unroll
    for (int i = 0; i < 64; i++) {
        int idx = tid + i * 256;
        int l = idx >> 6, n = idx & 63;
        bs[l][n] = ldf(&bmat[blbase * DS + idx]) * dec[l];
    }
    __syncthreads();
    float acc[64] = {};
    const bf16* xb = xdt + (blbase * DI) + h * HD;
    for (int l = 0; l < 256; l++) {
        float xv = ldf(&xb[(long)l * DI + tid]);
#pragma unroll
        for (int n = 0; n < 64; n++) acc[n] += bs[l][n] * xv;
    }
    float* so = st + (long)z * (HD * DS) + tid * DS;
#pragma unroll
    for (int n = 0; n < 64; n++) so[n] = acc[n];
}

// ---------------- serial chunk scan (in place) ----------------
__global__ void scan_kernel(float* __restrict__ st, const float* __restrict__ csum) {
    long idx = (long)blockIdx.x * 256 + threadIdx.x;
    int pn = (int)(idx & 16383);
    int h = (int)((idx >> 14) & 7);
    int b = (int)(idx >> 17);
    float S = 0.f;
    for (int c = 0; c < NC; c++) {
        long si = (((long)(b * NC + c) * NH + h) * (HD * DS)) + pn;
        float chunk = st[si];
        st[si] = S;
        S = S * expf(csum[(b * NH + h) * NC + c]) + chunk;
    }
}

// ---------------- fused SSD y via MFMA ----------------
// block = (zt, lt): zt = b*128 + c*8 + h; lt = l-tile (64 rows) in chunk.
// y[l,p] = sum_{s<=l} (c_l.b_s) exp(cumA_l-cumA_s) x[s,p] + exp(cumA_l)(c_l.S[p,:])
__global__ __launch_bounds__(256) void ssd_y_mfma(
        const bf16* __restrict__ bmat, const bf16* __restrict__ cmat,
        const bf16* __restrict__ xdt, const float* __restrict__ st,
        const float* __restrict__ cumA, bf16* __restrict__ y) {
    __shared__ __align__(16) bf16 cT[64][72];     // c rows l, cols n
    __shared__ __align__(16) bf16 bWt[64][72];    // phase 1: b rows s; phase 2: W rows l
    __shared__ __align__(16) bf16 XTt[256][72];   // X^T rows p, swizzled cols; also Y scratch
    __shared__ float cumL[64], cumS[64];

    const int t = threadIdx.x, lane = t & 63, w = t >> 6;
    const int bid = blockIdx.x;
    const int zt = bid >> 2, lt = bid & 3;
    const int h = zt & 7, c = (zt >> 3) & 15, b = zt >> 7;
    const long blr = (long)b * LL + (long)c * CHK;
    const int bhc = (b * NH + h) * NC + c;
    const int l0 = lt * 64;

    // stage c-tile + cumL
#pragma unroll
    for (int i = 0; i < 2; i++) {
        int u = t + i * 256; int row = u >> 3, n8 = (u & 7) * 8;
        *(uint4*)&cT[row][n8] = *(const uint4*)&cmat[(blr + l0 + row) * DS + n8];
    }
    if (t < 64) cumL[t] = cumA[(long)bhc * CHK + l0 + t];

    f4 acc[4][4];
#pragma unroll
    for (int mi = 0; mi < 4; mi++)
#pragma unroll
        for (int ni = 0; ni < 4; ni++) acc[mi][ni] = (f4){0.f, 0.f, 0.f, 0.f};
    __syncthreads();

    // ---- intra-chunk causal s-tiles ----
    for (int stile = 0; stile <= lt; stile++) {
        const int s0 = stile * 64;
        // stage b-tile into bWt
#pragma unroll
        for (int i = 0; i < 2; i++) {
            int u = t + i * 256; int row = u >> 3, n8 = (u & 7) * 8;
            *(uint4*)&bWt[row][n8] = *(const uint4*)&bmat[(blr + s0 + row) * DS + n8];
        }
        if (t < 64) cumS[t] = cumA[(long)bhc * CHK + s0 + t];
        // stage X^T tile (transpose xdt[s][p] -> XTt[p][s^swz])
#pragma unroll
        for (int i = 0; i < 8; i++) {
            int u = t + i * 256; int s = u >> 5, p8 = u & 31;
            bf16 v[8];
            *(uint4*)v = *(const uint4*)&xdt[(blr + s0 + s) * DI + h * HD + p8 * 8];
            int col = s ^ ((p8 & 7) << 3);
#pragma unroll
            for (int j = 0; j < 8; j++) XTt[p8 * 8 + j][col] = v[j];
        }
        __syncthreads();

        // W-gemm: wave w computes W rows [w*16, w*16+16) x 64 s, K=64 (n)
        f4 wacc[4];
#pragma unroll
        for (int ni = 0; ni < 4; ni++) wacc[ni] = (f4){0.f, 0.f, 0.f, 0.f};
#pragma unroll
        for (int ks = 0; ks < 2; ks++) {
            s8 af = *(const s8*)&cT[w * 16 + (lane & 15)][ks * 32 + (lane >> 4) * 8];
#pragma unroll
            for (int ni = 0; ni < 4; ni++) {
                s8 bfr = *(const s8*)&bWt[ni * 16 + (lane & 15)][ks * 32 + (lane >> 4) * 8];
                wacc[ni] = mfma16(af, bfr, wacc[ni]);
            }
        }
        __syncthreads();  // all MFMA reads of b-tile done before overwrite

        // epilogue: decay+mask, write W (bf16) into bWt
#pragma unroll
        for (int ni = 0; ni < 4; ni++) {
            int s_idx = ni * 16 + (lane & 15);
#pragma unroll
            for (int r = 0; r < 4; r++) {
                int l_loc = w * 16 + (lane >> 4) * 4 + r;
                bool valid = (stile < lt) || (l_loc >= s_idx);
                float val = valid ? wacc[ni][r] * expf(cumL[l_loc] - cumS[s_idx]) : 0.f;
                bWt[l_loc][s_idx] = __float2bfloat16(val);
            }
        }
        __syncthreads();

        // Y-gemm: wave w: all 64 l x p-range [w*64, w*64+64), K=64 (s)
#pragma unroll
        for (int ks = 0; ks < 2; ks++) {
            s8 aw[4], bx[4];
#pragma unroll
            for (int mi = 0; mi < 4; mi++)
                aw[mi] = *(const s8*)&bWt[mi * 16 + (lane & 15)][ks * 32 + (lane >> 4) * 8];
#pragma unroll
            for (int ni = 0; ni < 4; ni++) {
                int p = w * 64 + ni * 16 + (lane & 15);
                int cb = (ks * 32 + (lane >> 4) * 8) ^ (((p >> 3) & 7) << 3);
                bx[ni] = *(const s8*)&XTt[p][cb];
            }
#pragma unroll
            for (int mi = 0; mi < 4; mi++)
#pragma unroll
                for (int ni = 0; ni < 4; ni++)
                    acc[mi][ni] = mfma16(aw[mi], bx[ni], acc[mi][ni]);
        }
        __syncthreads();
    }

    // ---- inter-chunk state tile: W = c*exp(cumL), X = St^T ----
#pragma unroll
    for (int i = 0; i < 16; i++) {
        int u = t + i * 256; int l = u >> 6, n = u & 63;
        bWt[l][n] = __float2bfloat16(__bfloat162float(cT[l][n]) * expf(cumL[l]));
    }
    {
        const float* sp = st + (long)zt * (HD * DS) + t * DS;
        int kap = ((t >> 3) & 7) << 3;
#pragma unroll
        for (int g = 0; g < 8; g++) {
            float4 a = *(const float4*)&sp[g * 8];
            float4 bq = *(const float4*)&sp[g * 8 + 4];
            bf16 v[8];
            v[0] = __float2bfloat16(a.x); v[1] = __float2bfloat16(a.y);
            v[2] = __float2bfloat16(a.z); v[3] = __float2bfloat16(a.w);
            v[4] = __float2bfloat16(bq.x); v[5] = __float2bfloat16(bq.y);
            v[6] = __float2bfloat16(bq.z); v[7] = __float2bfloat16(bq.w);
            *(uint4*)&XTt[t][(g * 8) ^ kap] = *(uint4*)v;
        }
    }
    __syncthreads();
#pragma unroll
    for (int ks = 0; ks < 2; ks++) {
        s8 aw[4], bx[4];
#pragma unroll
        for (int mi = 0; mi < 4; mi++)
            aw[mi] = *(const s8*)&bWt[mi * 16 + (lane & 15)][ks * 32 + (lane >> 4) * 8];
#pragma unroll
        for (int ni = 0; ni < 4; ni++) {
            int p = w * 64 + ni * 16 + (lane & 15);
            int cb = (ks * 32 + (lane >> 4) * 8) ^ (((p >> 3) & 7) << 3);
            bx[ni] = *(const s8*)&XTt[p][cb];
        }
#pragma unroll
        for (int mi = 0; mi < 4; mi++)
#pragma unroll
            for (int ni = 0; ni < 4; ni++)
                acc[mi][ni] = mfma16(aw[mi], bx[ni], acc[mi][ni]);
    }
    __syncthreads();

    // ---- epilogue: frags -> LDS -> coalesced global (y bf16, [MROWS][DI]) ----
    bf16* Yl = (bf16*)XTt;
#pragma unroll
    for (int mi = 0; mi < 4; mi++)
#pragma unroll
        for (int ni = 0; ni < 4; ni++)
#pragma unroll
            for (int r = 0; r < 4; r++)
                Yl[(mi * 16 + (lane >> 4) * 4 + r) * 256 + w * 64 + ni * 16 + (lane & 15)] =
                    __float2bfloat16(acc[mi][ni][r]);
    __syncthreads();
#pragma unroll
    for (int i = 0; i < 8; i++) {
        int u = t + i * 256; int l = u >> 5, p8 = u & 31;
        *(uint4*)&y[(blr + l0 + l) * DI + h * HD + p8 * 8] = *(uint4*)&Yl[l * 256 + p8 * 8];
    }
}

// ---------------- gate (silu(z)) + RMSNorm (in-place capable) ----------------
__global__ void gatenorm_kernel(const bf16* __restrict__ y, const bf16* __restrict__ z,
                                const float* __restrict__ gamma, bf16* __restrict__ out) {
    int row = blockIdx.x;
    int tid = threadIdx.x;
    float g[8];
    float ss = 0.f;
#pragma unroll
    for (int i = 0; i < 8; i++) {
        int d = tid + i * 256;
        float yv = ldf(&y[(long)row * DI + d]);
        float zv = ldf(&z[(long)row * DI + d]);
        float gate = zv / (1.f + expf(-zv));
        float v = yv * gate;
        g[i] = v;
        ss += v * v;
    }
#pragma unroll
    for (int off = 32; off > 0; off >>= 1) ss += __shfl_down(ss, off);
    __shared__ float red[4];
    if ((tid & 63) == 0) red[tid >> 6] = ss;
    __syncthreads();
    float tot = red[0] + red[1] + red[2] + red[3];
    float scale = rsqrtf(tot / (float)DI + 1e-5f);
#pragma unroll
    for (int i = 0; i < 8; i++) {
        int d = tid + i * 256;
        stf(&out[(long)row * DI + d], g[i] * scale * gamma[d]);
    }
}

extern "C" void kernel_launch(void* const* d_in, const int* in_sizes, int n_in,
                              void* d_out, int out_size, void* d_ws, size_t ws_size,
                              hipStream_t stream) {
    const float* inputs = (const float*)d_in[0];
    const float* Wz = (const float*)d_in[1];
    const float* Wxbc = (const float*)d_in[2];
    const float* Wdt = (const float*)d_in[3];
    const float* conv_kernel = (const float*)d_in[4];
    const float* dt_bias = (const float*)d_in[5];
    const float* a_log = (const float*)d_in[6];
    const float* gamma = (const float*)d_in[7];
    const float* Wout = (const float*)d_in[8];
    float* out = (float*)d_out;

    // ---- workspace layout (~191 MiB) ----
    char* p = (char*)d_ws;
    float* dtb = (float*)p;      p += (long)MROWS * NH * 4;
    float* cumA = (float*)p;     p += (long)MROWS * NH * 4;
    float* csum = (float*)p;     p += 512 * 4;
    float* st = (float*)p;       p += (long)BB * NC * NH * HD * DS * 4;   // 33.5 MB
    bf16* inA = (bf16*)p;        p += (long)MROWS * DM * 2;               // 16.8 MB
    bf16* WzT = (bf16*)p;        p += (long)DI * DM * 2;
    bf16* WxbcT = (bf16*)p;      p += (long)CONVD * DM * 2;
    bf16* WoutT = (bf16*)p;      p += (long)DM * DI * 2;
    bf16* bmat = (bf16*)p;       p += (long)MROWS * DS * 2;
    bf16* cmat = (bf16*)p;       p += (long)MROWS * DS * 2;
    bf16* xbcy = (bf16*)p;       p += (long)MROWS * CONVD * 2;  // xbc -> y
    bf16* xdtz = (bf16*)p;       p += (long)MROWS * DI * 2;     // x*dt -> z -> ynorm
    bf16* ybuf = xbcy;

    // 1. casts / weight transposes
    cast_bf16_kernel<<<MROWS * DM / 8 / 256, 256, 0, stream>>>(inputs, inA);
    tcast_kernel<<<dim3(DI / 64, DM / 64), 256, 0, stream>>>(Wz, WzT, DM, DI);
    tcast_kernel<<<dim3(CONVD / 64, DM / 64), 256, 0, stream>>>(Wxbc, WxbcT, DM, CONVD);
    tcast_kernel<<<dim3(DM / 64, DI / 64), 256, 0, stream>>>(Wout, WoutT, DI, DM);
    // 2. xbc = inA @ Wxbc
    mfma_gemm<bf16><<<dim3(CONVD / 128, MROWS / 128), 256, 0, stream>>>(inA, WxbcT, xbcy, CONVD, DM);
    // 3. dt
    dt_kernel<<<MROWS * NH / 256, 256, 0, stream>>>(inputs, Wdt, dt_bias, dtb);
    // 4. conv + silu + split + x*dt
    long convtot = (long)MROWS * CONVD;
    conv_silu_split<<<(unsigned)((convtot + 255) / 256), 256, 0, stream>>>(xbcy, conv_kernel, dtb, xdtz, bmat, cmat);
    // 5. cumsum
    cumsum_kernel<<<2, 256, 0, stream>>>(dtb, a_log, cumA, csum);
    // 6. per-chunk states
    states_kernel<<<BB * NC * NH, 256, 0, stream>>>(bmat, xdtz, cumA, csum, st);
    // 7. chunk scan (in place)
    scan_kernel<<<BB * NH * HD * DS / 256, 256, 0, stream>>>(st, csum);
    // 8. fused SSD y (MFMA) -> ybuf (over dead xbc)
    ssd_y_mfma<<<BB * NC * NH * 4, 256, 0, stream>>>(bmat, cmat, xdtz, st, cumA, ybuf);
    // 9. z = inA @ Wz (over dead x*dt)
    mfma_gemm<bf16><<<dim3(DI / 128, MROWS / 128), 256, 0, stream>>>(inA, WzT, xdtz, DI, DM);
    // 10. gate + rmsnorm (ynorm in-place over z)
    gatenorm_kernel<<<MROWS, 256, 0, stream>>>(ybuf, xdtz, gamma, xdtz);
    // 11. out = ynorm @ Wout
    mfma_gemm<float><<<dim3(DM / 128, MROWS / 128), 256, 0, stream>>>(xdtz, WoutT, out, DM, DI);
}

// Round 4
// 519.777 us; speedup vs baseline: 11.0610x; 1.4460x over previous
//
#include <hip/hip_runtime.h>
#include <hip/hip_bf16.h>

// Mamba2 block forward. B=4 L=4096 D_MODEL=512 D_INNER=2048 H=8 P=256 N=64
// CHUNK=256 C=16 CONV_DIM=2176.
// Round 4: states -> MFMA (was 206us f32 VALU kernel); vectorized conv /
// gatenorm / dt (guideline-13). Workspace ~191 MiB.

#define BB 4
#define LL 4096
#define DM 512
#define DI 2048
#define NH 8
#define HD 256
#define DS 64
#define DCONV 4
#define CHK 256
#define NC 16
#define CONVD 2176
#define MROWS (BB*LL)   // 16384

typedef __hip_bfloat16 bf16;
typedef short s8 __attribute__((ext_vector_type(8)));   // 8 bf16 (4 VGPRs)
typedef float f4 __attribute__((ext_vector_type(4)));   // MFMA acc

__device__ __forceinline__ f4 mfma16(s8 a, s8 b, f4 c) {
    return __builtin_amdgcn_mfma_f32_16x16x32_bf16(a, b, c, 0, 0, 0);
}

__device__ __forceinline__ float ldf(const float* p) { return *p; }
__device__ __forceinline__ float ldf(const bf16* p) { return __bfloat162float(*p); }
__device__ __forceinline__ void stf(float* p, float v) { *p = v; }
__device__ __forceinline__ void stf(bf16* p, float v) { *p = __float2bfloat16(v); }

// ---------------- f32 -> bf16 cast (elementwise, 8/thread) ----------------
__global__ void cast_bf16_kernel(const float* __restrict__ in, bf16* __restrict__ out) {
    long i8 = ((long)blockIdx.x * 256 + threadIdx.x) * 8;
    float4 a = *(const float4*)&in[i8];
    float4 b = *(const float4*)&in[i8 + 4];
    bf16 v[8];
    v[0] = __float2bfloat16(a.x); v[1] = __float2bfloat16(a.y);
    v[2] = __float2bfloat16(a.z); v[3] = __float2bfloat16(a.w);
    v[4] = __float2bfloat16(b.x); v[5] = __float2bfloat16(b.y);
    v[6] = __float2bfloat16(b.z); v[7] = __float2bfloat16(b.w);
    *(uint4*)&out[i8] = *(uint4*)v;
}

// ---------------- f32 [K][N] -> bf16 [N][K] transpose-cast ----------------
__global__ void tcast_kernel(const float* __restrict__ in, bf16* __restrict__ out,
                             int K, int N) {
    __shared__ float tile[64][65];
    int t = threadIdx.x;
    int n0 = blockIdx.x * 64, k0 = blockIdx.y * 64;
#pragma unroll
    for (int i = 0; i < 16; i++) {
        int u = t + i * 256; int kr = u >> 6, nc = u & 63;
        tile[kr][nc] = in[(long)(k0 + kr) * N + n0 + nc];
    }
    __syncthreads();
#pragma unroll
    for (int i = 0; i < 16; i++) {
        int u = t + i * 256; int nr = u >> 6, kc = u & 63;
        out[(long)(n0 + nr) * K + k0 + kc] = __float2bfloat16(tile[kc][nr]);
    }
}

// ---------------- bf16 MFMA GEMM: C[M][N] = A[M][K] @ BT[N][K]^T ----------------
template <typename TC>
__global__ __launch_bounds__(256) void mfma_gemm(const bf16* __restrict__ A,
                                                 const bf16* __restrict__ BT,
                                                 TC* __restrict__ C, int N, int K) {
    __shared__ __align__(16) bf16 At[128][72];
    __shared__ __align__(16) bf16 Bt[128][72];
    const int t = threadIdx.x, lane = t & 63, w = t >> 6;
    const int wr = w >> 1, wc = w & 1;
    const long m0 = (long)blockIdx.y * 128;
    const int n0 = blockIdx.x * 128;
    f4 acc[4][4];
#pragma unroll
    for (int mi = 0; mi < 4; mi++)
#pragma unroll
        for (int ni = 0; ni < 4; ni++) acc[mi][ni] = (f4){0.f, 0.f, 0.f, 0.f};

    for (int k0 = 0; k0 < K; k0 += 64) {
#pragma unroll
        for (int i = 0; i < 4; i++) {
            int u = t + i * 256; int m = u >> 3, k8 = (u & 7) * 8;
            *(uint4*)&At[m][k8] = *(const uint4*)&A[(m0 + m) * (long)K + k0 + k8];
            *(uint4*)&Bt[m][k8] = *(const uint4*)&BT[((long)n0 + m) * K + k0 + k8];
        }
        __syncthreads();
#pragma unroll
        for (int ks = 0; ks < 2; ks++) {
            s8 af[4], bfr[4];
#pragma unroll
            for (int mi = 0; mi < 4; mi++)
                af[mi] = *(const s8*)&At[wr * 64 + mi * 16 + (lane & 15)][ks * 32 + (lane >> 4) * 8];
#pragma unroll
            for (int ni = 0; ni < 4; ni++)
                bfr[ni] = *(const s8*)&Bt[wc * 64 + ni * 16 + (lane & 15)][ks * 32 + (lane >> 4) * 8];
#pragma unroll
            for (int mi = 0; mi < 4; mi++)
#pragma unroll
                for (int ni = 0; ni < 4; ni++)
                    acc[mi][ni] = mfma16(af[mi], bfr[ni], acc[mi][ni]);
        }
        __syncthreads();
    }
#pragma unroll
    for (int mi = 0; mi < 4; mi++)
#pragma unroll
        for (int ni = 0; ni < 4; ni++)
#pragma unroll
            for (int r = 0; r < 4; r++)
                stf(&C[(m0 + wr * 64 + mi * 16 + (lane >> 4) * 4 + r) * (long)N +
                       n0 + wc * 64 + ni * 16 + (lane & 15)], acc[mi][ni][r]);
}

// ---------------- dt = softplus(inputs @ Wdt + bias) ----------------
__global__ void dt_kernel(const float* __restrict__ inp, const float* __restrict__ Wdt,
                          const float* __restrict__ dt_bias, float* __restrict__ dtb) {
    __shared__ float wlds[DM * NH];  // 16 KB
    int t = threadIdx.x;
#pragma unroll
    for (int i = 0; i < 16; i++) wlds[t + i * 256] = Wdt[t + i * 256];
    __syncthreads();
    int idx = blockIdx.x * 256 + t;
    int h = idx & 7;
    long row = idx >> 3;
    const float* ir = inp + row * DM;
    float acc = 0.f;
    for (int k = 0; k < DM; k += 4) {
        float4 a = *(const float4*)&ir[k];
        acc += a.x * wlds[k * 8 + h] + a.y * wlds[(k + 1) * 8 + h]
             + a.z * wlds[(k + 2) * 8 + h] + a.w * wlds[(k + 3) * 8 + h];
    }
    acc += dt_bias[h];
    float sp = acc > 20.f ? acc : log1pf(expf(acc));
    dtb[idx] = sp;
}

// ---------------- conv(4) + silu + split + x*dt (8 ch / thread) ----------------
__global__ void conv_silu_split(const bf16* __restrict__ xbc, const float* __restrict__ ck,
                                const float* __restrict__ dtb, bf16* __restrict__ xdt,
                                bf16* __restrict__ bm, bf16* __restrict__ cm) {
    long idx = (long)blockIdx.x * 256 + threadIdx.x;   // MROWS*CONVD/8 threads
    if (idx >= (long)MROWS * CONVD / 8) return;
    long e0 = idx * 8;
    int ch = (int)(e0 % CONVD);
    long bl = e0 / CONVD;
    int l = (int)(bl % LL);
    float acc[8] = {};
#pragma unroll
    for (int k = 0; k < DCONV; k++) {
        int ls = l - 3 + k;
        if (ls >= 0) {
            bf16 v[8];
            *(uint4*)v = *(const uint4*)&xbc[(bl - l + ls) * CONVD + ch];
            float4 c0 = *(const float4*)&ck[k * CONVD + ch];
            float4 c1 = *(const float4*)&ck[k * CONVD + ch + 4];
            acc[0] += __bfloat162float(v[0]) * c0.x;
            acc[1] += __bfloat162float(v[1]) * c0.y;
            acc[2] += __bfloat162float(v[2]) * c0.z;
            acc[3] += __bfloat162float(v[3]) * c0.w;
            acc[4] += __bfloat162float(v[4]) * c1.x;
            acc[5] += __bfloat162float(v[5]) * c1.y;
            acc[6] += __bfloat162float(v[6]) * c1.z;
            acc[7] += __bfloat162float(v[7]) * c1.w;
        }
    }
    bf16 o[8];
    if (ch < DI) {
        float dt = dtb[bl * NH + (ch >> 8)];
#pragma unroll
        for (int j = 0; j < 8; j++) {
            float s = acc[j] / (1.f + expf(-acc[j]));
            o[j] = __float2bfloat16(s * dt);
        }
        *(uint4*)&xdt[bl * DI + ch] = *(uint4*)o;
    } else {
#pragma unroll
        for (int j = 0; j < 8; j++) {
            float s = acc[j] / (1.f + expf(-acc[j]));
            o[j] = __float2bfloat16(s);
        }
        if (ch < DI + DS) *(uint4*)&bm[bl * DS + (ch - DI)] = *(uint4*)o;
        else              *(uint4*)&cm[bl * DS + (ch - DI - DS)] = *(uint4*)o;
    }
}

// ---------------- per-(b,h,c) cumsum of a*dt ----------------
__global__ void cumsum_kernel(const float* __restrict__ dtb, const float* __restrict__ a_log,
                              float* __restrict__ cumA, float* __restrict__ csum) {
    int t = blockIdx.x * 256 + threadIdx.x;  // t = b*128 + h*16 + c
    if (t >= BB * NH * NC) return;
    int c = t & 15, h = (t >> 4) & 7, b = t >> 7;
    float a = -expf(a_log[h]);
    long base_l = (long)b * LL + (long)c * CHK;
    float s = 0.f;
    long obase = (long)t * CHK;
    for (int i = 0; i < CHK; i++) {
        s += a * dtb[(base_l + i) * NH + h];
        cumA[obase + i] = s;
    }
    csum[t] = s;
}

// ---------------- states via MFMA: st[p][n] = sum_l x[l,p]*b[l,n]*dec[l] ----------------
// One block per (b,c,h). A-operand = bdec^T [n][l], B-operand = x^T [p][l].
__global__ __launch_bounds__(256) void states_mfma(
        const bf16* __restrict__ bmat, const bf16* __restrict__ xdt,
        const float* __restrict__ cumA, const float* __restrict__ csum,
        float* __restrict__ st) {
    __shared__ __align__(16) bf16 XT[256][72];  // p rows, l-tile cols (XOR-swizzled)
    __shared__ __align__(16) bf16 BT[64][72];   // n rows, l-tile cols (XOR-swizzled)
    const int z = blockIdx.x;  // b*128 + c*8 + h
    const int h = z & 7, c = (z >> 3) & 15, b = z >> 7;
    const long blr = (long)b * LL + (long)c * CHK;
    const int bhc = (b * NH + h) * NC + c;
    const float A = csum[bhc];
    const int t = threadIdx.x, lane = t & 63, w = t >> 6;
    f4 acc[4][4];
#pragma unroll
    for (int mi = 0; mi < 4; mi++)
#pragma unroll
        for (int ni = 0; ni < 4; ni++) acc[mi][ni] = (f4){0.f, 0.f, 0.f, 0.f};

    for (int lt = 0; lt < 4; lt++) {
        const int l0 = lt * 64;
        // stage bdec^T: read b rows (l, n-contig), scale by dec[l], scatter to BT[n][l^swz]
#pragma unroll
        for (int i = 0; i < 2; i++) {
            int u = t + i * 256;           // [0,512)
            int l = u >> 3, n8 = (u & 7) * 8;
            bf16 v[8];
            *(uint4*)v = *(const uint4*)&bmat[(blr + l0 + l) * DS + n8];
            float d = expf(A - cumA[(long)bhc * CHK + l0 + l]);
#pragma unroll
            for (int j = 0; j < 8; j++) {
                int n = n8 + j;
                BT[n][l ^ ((n & 7) << 3)] = __float2bfloat16(__bfloat162float(v[j]) * d);
            }
        }
        // stage x^T: read x rows (l, p-contig), scatter to XT[p][l^swz]
#pragma unroll
        for (int i = 0; i < 8; i++) {
            int u = t + i * 256;           // [0,2048)
            int l = u >> 5, p8 = (u & 31) * 8;
            bf16 v[8];
            *(uint4*)v = *(const uint4*)&xdt[(blr + l0 + l) * DI + h * HD + p8];
#pragma unroll
            for (int j = 0; j < 8; j++) {
                int pp = p8 + j;
                XT[pp][l ^ ((pp & 7) << 3)] = v[j];
            }
        }
        __syncthreads();
#pragma unroll
        for (int ks = 0; ks < 2; ks++) {
            s8 af[4], bx[4];
#pragma unroll
            for (int mi = 0; mi < 4; mi++) {
                int n = mi * 16 + (lane & 15);
                af[mi] = *(const s8*)&BT[n][(ks * 32 + (lane >> 4) * 8) ^ ((n & 7) << 3)];
            }
#pragma unroll
            for (int ni = 0; ni < 4; ni++) {
                int p = w * 64 + ni * 16 + (lane & 15);
                bx[ni] = *(const s8*)&XT[p][(ks * 32 + (lane >> 4) * 8) ^ ((p & 7) << 3)];
            }
#pragma unroll
            for (int mi = 0; mi < 4; mi++)
#pragma unroll
                for (int ni = 0; ni < 4; ni++)
                    acc[mi][ni] = mfma16(af[mi], bx[ni], acc[mi][ni]);
        }
        __syncthreads();
    }
    // D rows = n, cols = p; write st[p][n] (transposed), float4 along n
    float* so = st + (long)z * (HD * DS);
#pragma unroll
    for (int mi = 0; mi < 4; mi++)
#pragma unroll
        for (int ni = 0; ni < 4; ni++) {
            int p = w * 64 + ni * 16 + (lane & 15);
            int n0 = mi * 16 + (lane >> 4) * 4;
            float4 vv = {acc[mi][ni][0], acc[mi][ni][1], acc[mi][ni][2], acc[mi][ni][3]};
            *(float4*)&so[p * 64 + n0] = vv;
        }
}

// ---------------- serial chunk scan (in place) ----------------
__global__ void scan_kernel(float* __restrict__ st, const float* __restrict__ csum) {
    long idx = (long)blockIdx.x * 256 + threadIdx.x;
    int pn = (int)(idx & 16383);
    int h = (int)((idx >> 14) & 7);
    int b = (int)(idx >> 17);
    float S = 0.f;
    for (int c = 0; c < NC; c++) {
        long si = (((long)(b * NC + c) * NH + h) * (HD * DS)) + pn;
        float chunk = st[si];
        st[si] = S;
        S = S * expf(csum[(b * NH + h) * NC + c]) + chunk;
    }
}

// ---------------- fused SSD y via MFMA ----------------
__global__ __launch_bounds__(256) void ssd_y_mfma(
        const bf16* __restrict__ bmat, const bf16* __restrict__ cmat,
        const bf16* __restrict__ xdt, const float* __restrict__ st,
        const float* __restrict__ cumA, bf16* __restrict__ y) {
    __shared__ __align__(16) bf16 cT[64][72];     // c rows l, cols n
    __shared__ __align__(16) bf16 bWt[64][72];    // phase 1: b rows s; phase 2: W rows l
    __shared__ __align__(16) bf16 XTt[256][72];   // X^T rows p, swizzled cols; also Y scratch
    __shared__ float cumL[64], cumS[64];

    const int t = threadIdx.x, lane = t & 63, w = t >> 6;
    const int bid = blockIdx.x;
    const int zt = bid >> 2, lt = bid & 3;
    const int h = zt & 7, c = (zt >> 3) & 15, b = zt >> 7;
    const long blr = (long)b * LL + (long)c * CHK;
    const int bhc = (b * NH + h) * NC + c;
    const int l0 = lt * 64;

#pragma unroll
    for (int i = 0; i < 2; i++) {
        int u = t + i * 256; int row = u >> 3, n8 = (u & 7) * 8;
        *(uint4*)&cT[row][n8] = *(const uint4*)&cmat[(blr + l0 + row) * DS + n8];
    }
    if (t < 64) cumL[t] = cumA[(long)bhc * CHK + l0 + t];

    f4 acc[4][4];
#pragma unroll
    for (int mi = 0; mi < 4; mi++)
#pragma unroll
        for (int ni = 0; ni < 4; ni++) acc[mi][ni] = (f4){0.f, 0.f, 0.f, 0.f};
    __syncthreads();

    for (int stile = 0; stile <= lt; stile++) {
        const int s0 = stile * 64;
#pragma unroll
        for (int i = 0; i < 2; i++) {
            int u = t + i * 256; int row = u >> 3, n8 = (u & 7) * 8;
            *(uint4*)&bWt[row][n8] = *(const uint4*)&bmat[(blr + s0 + row) * DS + n8];
        }
        if (t < 64) cumS[t] = cumA[(long)bhc * CHK + s0 + t];
#pragma unroll
        for (int i = 0; i < 8; i++) {
            int u = t + i * 256; int s = u >> 5, p8 = u & 31;
            bf16 v[8];
            *(uint4*)v = *(const uint4*)&xdt[(blr + s0 + s) * DI + h * HD + p8 * 8];
            int col = s ^ ((p8 & 7) << 3);
#pragma unroll
            for (int j = 0; j < 8; j++) XTt[p8 * 8 + j][col] = v[j];
        }
        __syncthreads();

        f4 wacc[4];
#pragma unroll
        for (int ni = 0; ni < 4; ni++) wacc[ni] = (f4){0.f, 0.f, 0.f, 0.f};
#pragma unroll
        for (int ks = 0; ks < 2; ks++) {
            s8 af = *(const s8*)&cT[w * 16 + (lane & 15)][ks * 32 + (lane >> 4) * 8];
#pragma unroll
            for (int ni = 0; ni < 4; ni++) {
                s8 bfr = *(const s8*)&bWt[ni * 16 + (lane & 15)][ks * 32 + (lane >> 4) * 8];
                wacc[ni] = mfma16(af, bfr, wacc[ni]);
            }
        }
        __syncthreads();

#pragma unroll
        for (int ni = 0; ni < 4; ni++) {
            int s_idx = ni * 16 + (lane & 15);
#pragma unroll
            for (int r = 0; r < 4; r++) {
                int l_loc = w * 16 + (lane >> 4) * 4 + r;
                bool valid = (stile < lt) || (l_loc >= s_idx);
                float val = valid ? wacc[ni][r] * expf(cumL[l_loc] - cumS[s_idx]) : 0.f;
                bWt[l_loc][s_idx] = __float2bfloat16(val);
            }
        }
        __syncthreads();

#pragma unroll
        for (int ks = 0; ks < 2; ks++) {
            s8 aw[4], bx[4];
#pragma unroll
            for (int mi = 0; mi < 4; mi++)
                aw[mi] = *(const s8*)&bWt[mi * 16 + (lane & 15)][ks * 32 + (lane >> 4) * 8];
#pragma unroll
            for (int ni = 0; ni < 4; ni++) {
                int p = w * 64 + ni * 16 + (lane & 15);
                int cb = (ks * 32 + (lane >> 4) * 8) ^ (((p >> 3) & 7) << 3);
                bx[ni] = *(const s8*)&XTt[p][cb];
            }
#pragma unroll
            for (int mi = 0; mi < 4; mi++)
#pragma unroll
                for (int ni = 0; ni < 4; ni++)
                    acc[mi][ni] = mfma16(aw[mi], bx[ni], acc[mi][ni]);
        }
        __syncthreads();
    }

    // inter-chunk state tile
#pragma unroll
    for (int i = 0; i < 16; i++) {
        int u = t + i * 256; int l = u >> 6, n = u & 63;
        bWt[l][n] = __float2bfloat16(__bfloat162float(cT[l][n]) * expf(cumL[l]));
    }
    {
        const float* sp = st + (long)zt * (HD * DS) + t * DS;
        int kap = ((t >> 3) & 7) << 3;
#pragma unroll
        for (int g = 0; g < 8; g++) {
            float4 a = *(const float4*)&sp[g * 8];
            float4 bq = *(const float4*)&sp[g * 8 + 4];
            bf16 v[8];
            v[0] = __float2bfloat16(a.x); v[1] = __float2bfloat16(a.y);
            v[2] = __float2bfloat16(a.z); v[3] = __float2bfloat16(a.w);
            v[4] = __float2bfloat16(bq.x); v[5] = __float2bfloat16(bq.y);
            v[6] = __float2bfloat16(bq.z); v[7] = __float2bfloat16(bq.w);
            *(uint4*)&XTt[t][(g * 8) ^ kap] = *(uint4*)v;
        }
    }
    __syncthreads();
#pragma unroll
    for (int ks = 0; ks < 2; ks++) {
        s8 aw[4], bx[4];
#pragma unroll
        for (int mi = 0; mi < 4; mi++)
            aw[mi] = *(const s8*)&bWt[mi * 16 + (lane & 15)][ks * 32 + (lane >> 4) * 8];
#pragma unroll
        for (int ni = 0; ni < 4; ni++) {
            int p = w * 64 + ni * 16 + (lane & 15);
            int cb = (ks * 32 + (lane >> 4) * 8) ^ (((p >> 3) & 7) << 3);
            bx[ni] = *(const s8*)&XTt[p][cb];
        }
#pragma unroll
        for (int mi = 0; mi < 4; mi++)
#pragma unroll
            for (int ni = 0; ni < 4; ni++)
                acc[mi][ni] = mfma16(aw[mi], bx[ni], acc[mi][ni]);
    }
    __syncthreads();

    bf16* Yl = (bf16*)XTt;
#pragma unroll
    for (int mi = 0; mi < 4; mi++)
#pragma unroll
        for (int ni = 0; ni < 4; ni++)
#pragma unroll
            for (int r = 0; r < 4; r++)
                Yl[(mi * 16 + (lane >> 4) * 4 + r) * 256 + w * 64 + ni * 16 + (lane & 15)] =
                    __float2bfloat16(acc[mi][ni][r]);
    __syncthreads();
#pragma unroll
    for (int i = 0; i < 8; i++) {
        int u = t + i * 256; int l = u >> 5, p8 = u & 31;
        *(uint4*)&y[(blr + l0 + l) * DI + h * HD + p8 * 8] = *(uint4*)&Yl[l * 256 + p8 * 8];
    }
}

// ---------------- gate (silu(z)) + RMSNorm, vectorized ----------------
__global__ void gatenorm_kernel(const bf16* __restrict__ y, const bf16* __restrict__ z,
                                const float* __restrict__ gamma, bf16* __restrict__ out) {
    int row = blockIdx.x;
    int tid = threadIdx.x;
    int d0 = tid * 8;
    bf16 yv[8], zv[8];
    *(uint4*)yv = *(const uint4*)&y[(long)row * DI + d0];
    *(uint4*)zv = *(const uint4*)&z[(long)row * DI + d0];
    float g[8];
    float ss = 0.f;
#pragma unroll
    for (int i = 0; i < 8; i++) {
        float zf = __bfloat162float(zv[i]);
        float gate = zf / (1.f + expf(-zf));
        float v = __bfloat162float(yv[i]) * gate;
        g[i] = v;
        ss += v * v;
    }
#pragma unroll
    for (int off = 32; off > 0; off >>= 1) ss += __shfl_down(ss, off);
    __shared__ float red[4];
    if ((tid & 63) == 0) red[tid >> 6] = ss;
    __syncthreads();
    float tot = red[0] + red[1] + red[2] + red[3];
    float scale = rsqrtf(tot / (float)DI + 1e-5f);
    float4 g0 = *(const float4*)&gamma[d0];
    float4 g1 = *(const float4*)&gamma[d0 + 4];
    bf16 o[8];
    o[0] = __float2bfloat16(g[0] * scale * g0.x);
    o[1] = __float2bfloat16(g[1] * scale * g0.y);
    o[2] = __float2bfloat16(g[2] * scale * g0.z);
    o[3] = __float2bfloat16(g[3] * scale * g0.w);
    o[4] = __float2bfloat16(g[4] * scale * g1.x);
    o[5] = __float2bfloat16(g[5] * scale * g1.y);
    o[6] = __float2bfloat16(g[6] * scale * g1.z);
    o[7] = __float2bfloat16(g[7] * scale * g1.w);
    *(uint4*)&out[(long)row * DI + d0] = *(uint4*)o;
}

extern "C" void kernel_launch(void* const* d_in, const int* in_sizes, int n_in,
                              void* d_out, int out_size, void* d_ws, size_t ws_size,
                              hipStream_t stream) {
    const float* inputs = (const float*)d_in[0];
    const float* Wz = (const float*)d_in[1];
    const float* Wxbc = (const float*)d_in[2];
    const float* Wdt = (const float*)d_in[3];
    const float* conv_kernel = (const float*)d_in[4];
    const float* dt_bias = (const float*)d_in[5];
    const float* a_log = (const float*)d_in[6];
    const float* gamma = (const float*)d_in[7];
    const float* Wout = (const float*)d_in[8];
    float* out = (float*)d_out;

    // ---- workspace layout (~191 MiB) ----
    char* p = (char*)d_ws;
    float* dtb = (float*)p;      p += (long)MROWS * NH * 4;
    float* cumA = (float*)p;     p += (long)MROWS * NH * 4;
    float* csum = (float*)p;     p += 512 * 4;
    float* st = (float*)p;       p += (long)BB * NC * NH * HD * DS * 4;   // 33.5 MB
    bf16* inA = (bf16*)p;        p += (long)MROWS * DM * 2;               // 16.8 MB
    bf16* WzT = (bf16*)p;        p += (long)DI * DM * 2;
    bf16* WxbcT = (bf16*)p;      p += (long)CONVD * DM * 2;
    bf16* WoutT = (bf16*)p;      p += (long)DM * DI * 2;
    bf16* bmat = (bf16*)p;       p += (long)MROWS * DS * 2;
    bf16* cmat = (bf16*)p;       p += (long)MROWS * DS * 2;
    bf16* xbcy = (bf16*)p;       p += (long)MROWS * CONVD * 2;  // xbc -> y
    bf16* xdtz = (bf16*)p;       p += (long)MROWS * DI * 2;     // x*dt -> z -> ynorm
    bf16* ybuf = xbcy;

    // 1. casts / weight transposes
    cast_bf16_kernel<<<MROWS * DM / 8 / 256, 256, 0, stream>>>(inputs, inA);
    tcast_kernel<<<dim3(DI / 64, DM / 64), 256, 0, stream>>>(Wz, WzT, DM, DI);
    tcast_kernel<<<dim3(CONVD / 64, DM / 64), 256, 0, stream>>>(Wxbc, WxbcT, DM, CONVD);
    tcast_kernel<<<dim3(DM / 64, DI / 64), 256, 0, stream>>>(Wout, WoutT, DI, DM);
    // 2. xbc = inA @ Wxbc
    mfma_gemm<bf16><<<dim3(CONVD / 128, MROWS / 128), 256, 0, stream>>>(inA, WxbcT, xbcy, CONVD, DM);
    // 3. dt
    dt_kernel<<<MROWS * NH / 256, 256, 0, stream>>>(inputs, Wdt, dt_bias, dtb);
    // 4. conv + silu + split + x*dt
    long convtot = (long)MROWS * CONVD / 8;
    conv_silu_split<<<(unsigned)((convtot + 255) / 256), 256, 0, stream>>>(xbcy, conv_kernel, dtb, xdtz, bmat, cmat);
    // 5. cumsum
    cumsum_kernel<<<2, 256, 0, stream>>>(dtb, a_log, cumA, csum);
    // 6. per-chunk states (MFMA)
    states_mfma<<<BB * NC * NH, 256, 0, stream>>>(bmat, xdtz, cumA, csum, st);
    // 7. chunk scan (in place)
    scan_kernel<<<BB * NH * HD * DS / 256, 256, 0, stream>>>(st, csum);
    // 8. fused SSD y (MFMA) -> ybuf (over dead xbc)
    ssd_y_mfma<<<BB * NC * NH * 4, 256, 0, stream>>>(bmat, cmat, xdtz, st, cumA, ybuf);
    // 9. z = inA @ Wz (over dead x*dt)
    mfma_gemm<bf16><<<dim3(DI / 128, MROWS / 128), 256, 0, stream>>>(inA, WzT, xdtz, DI, DM);
    // 10. gate + rmsnorm (ynorm in-place over z)
    gatenorm_kernel<<<MROWS, 256, 0, stream>>>(ybuf, xdtz, gamma, xdtz);
    // 11. out = ynorm @ Wout
    mfma_gemm<float><<<dim3(DM / 128, MROWS / 128), 256, 0, stream>>>(xdtz, WoutT, out, DM, DI);
}

// Round 5
// 448.068 us; speedup vs baseline: 12.8312x; 1.1600x over previous
//
#include <hip/hip_runtime.h>
#include <hip/hip_bf16.h>

// Mamba2 block forward. B=4 L=4096 D_MODEL=512 D_INNER=2048 H=8 P=256 N=64
// CHUNK=256 C=16 CONV_DIM=2176.
// Round 5: global xdtT (x transposed) kills transpose-scatter bank conflicts;
// st -> bf16; mfma_gemm -> global_load_lds(16B) + source-XOR swizzle;
// XCD-aware block swizzle in ssd_y. Workspace ~223 MiB.

#define BB 4
#define LL 4096
#define DM 512
#define DI 2048
#define NH 8
#define HD 256
#define DS 64
#define DCONV 4
#define CHK 256
#define NC 16
#define CONVD 2176
#define MROWS (BB*LL)   // 16384

typedef __hip_bfloat16 bf16;
typedef short s8 __attribute__((ext_vector_type(8)));   // 8 bf16 (4 VGPRs)
typedef float f4 __attribute__((ext_vector_type(4)));   // MFMA acc

__device__ __forceinline__ f4 mfma16(s8 a, s8 b, f4 c) {
    return __builtin_amdgcn_mfma_f32_16x16x32_bf16(a, b, c, 0, 0, 0);
}

__device__ __forceinline__ void gload16(const bf16* g, bf16* l) {
    __builtin_amdgcn_global_load_lds(
        (const __attribute__((address_space(1))) void*)g,
        (__attribute__((address_space(3))) void*)l, 16, 0, 0);
}

__device__ __forceinline__ float ldf(const float* p) { return *p; }
__device__ __forceinline__ float ldf(const bf16* p) { return __bfloat162float(*p); }
__device__ __forceinline__ void stf(float* p, float v) { *p = v; }
__device__ __forceinline__ void stf(bf16* p, float v) { *p = __float2bfloat16(v); }

// ---------------- f32 -> bf16 cast (8/thread) ----------------
__global__ void cast_bf16_kernel(const float* __restrict__ in, bf16* __restrict__ out) {
    long i8 = ((long)blockIdx.x * 256 + threadIdx.x) * 8;
    float4 a = *(const float4*)&in[i8];
    float4 b = *(const float4*)&in[i8 + 4];
    bf16 v[8];
    v[0] = __float2bfloat16(a.x); v[1] = __float2bfloat16(a.y);
    v[2] = __float2bfloat16(a.z); v[3] = __float2bfloat16(a.w);
    v[4] = __float2bfloat16(b.x); v[5] = __float2bfloat16(b.y);
    v[6] = __float2bfloat16(b.z); v[7] = __float2bfloat16(b.w);
    *(uint4*)&out[i8] = *(uint4*)v;
}

// ---------------- f32 [K][N] -> bf16 [N][K] transpose-cast (weights) ----------------
__global__ void tcast_kernel(const float* __restrict__ in, bf16* __restrict__ out,
                             int K, int N) {
    __shared__ float tile[64][65];
    int t = threadIdx.x;
    int n0 = blockIdx.x * 64, k0 = blockIdx.y * 64;
#pragma unroll
    for (int i = 0; i < 16; i++) {
        int u = t + i * 256; int kr = u >> 6, nc = u & 63;
        tile[kr][nc] = in[(long)(k0 + kr) * N + n0 + nc];
    }
    __syncthreads();
#pragma unroll
    for (int i = 0; i < 16; i++) {
        int u = t + i * 256; int nr = u >> 6, kc = u & 63;
        out[(long)(n0 + nr) * K + k0 + kc] = __float2bfloat16(tile[kc][nr]);
    }
}

// ---------------- bf16 [MROWS][DI] -> bf16 [B*DI][LL] transpose (x*dt) ----------------
// xdtT[(b*DI + d)][l] = xdt[(b*LL + l)][d]
__global__ __launch_bounds__(256) void transpose_x(const bf16* __restrict__ xdt,
                                                   bf16* __restrict__ xdtT) {
    __shared__ bf16 tile[64][72];
    const int bid = blockIdx.x;            // b*(64*32) + lt*32 + dt
    const int dt = bid & 31, lt = (bid >> 5) & 63, b = bid >> 11;
    const int t = threadIdx.x;
    // read 64 l-rows x 64 d, store with block-XOR key (lr>>3)
#pragma unroll
    for (int i = 0; i < 2; i++) {
        int u = t + i * 256; int lr = u >> 3, d8 = u & 7;
        int bk = d8 ^ ((lr >> 3) & 7);
        *(uint4*)&tile[lr][bk * 8] =
            *(const uint4*)&xdt[((long)b * LL + lt * 64 + lr) * DI + dt * 64 + d8 * 8];
    }
    __syncthreads();
    // write 64 d-rows x 64 l
#pragma unroll
    for (int i = 0; i < 2; i++) {
        int u = t + i * 256; int dr = u >> 3, l8 = (u & 7) * 8;
        bf16 v[8];
#pragma unroll
        for (int j = 0; j < 8; j++) v[j] = tile[l8 + j][dr ^ ((u & 7) << 3)];
        *(uint4*)&xdtT[((long)b * DI + dt * 64 + dr) * LL + lt * 64 + l8] = *(uint4*)v;
    }
}

// ---------------- bf16 MFMA GEMM via global_load_lds + src-XOR swizzle ----------------
// C[M][N] = A[M][K] @ BT[N][K]^T. 128x128 tile, BK=64, 4 waves.
template <typename TC>
__global__ __launch_bounds__(256) void mfma_gemm(const bf16* __restrict__ A,
                                                 const bf16* __restrict__ BT,
                                                 TC* __restrict__ C, int N, int K) {
    __shared__ __align__(16) bf16 At[128][64];
    __shared__ __align__(16) bf16 Bt[128][64];
    const int t = threadIdx.x, lane = t & 63, w = t >> 6;
    const int wr = w >> 1, wc = w & 1;
    const long m0 = (long)blockIdx.y * 128;
    const int n0 = blockIdx.x * 128;
    const int lrow = lane >> 3, lblk = lane & 7;
    f4 acc[4][4];
#pragma unroll
    for (int mi = 0; mi < 4; mi++)
#pragma unroll
        for (int ni = 0; ni < 4; ni++) acc[mi][ni] = (f4){0.f, 0.f, 0.f, 0.f};

    for (int k0 = 0; k0 < K; k0 += 64) {
#pragma unroll
        for (int i = 0; i < 4; i++) {
            int rbase = w * 32 + i * 8;
            int row = rbase + lrow;
            int kb = (lblk ^ (row & 7)) << 3;   // source k-block, pre-swizzled
            gload16(&A[(m0 + row) * (long)K + k0 + kb], &At[rbase][0]);
            gload16(&BT[((long)n0 + row) * K + k0 + kb], &Bt[rbase][0]);
        }
        __syncthreads();
#pragma unroll
        for (int ks = 0; ks < 2; ks++) {
            int k8 = ks * 4 + (lane >> 4);
            s8 af[4], bfr[4];
#pragma unroll
            for (int mi = 0; mi < 4; mi++) {
                int row = wr * 64 + mi * 16 + (lane & 15);
                af[mi] = *(const s8*)&At[row][(k8 ^ (row & 7)) << 3];
            }
#pragma unroll
            for (int ni = 0; ni < 4; ni++) {
                int row = wc * 64 + ni * 16 + (lane & 15);
                bfr[ni] = *(const s8*)&Bt[row][(k8 ^ (row & 7)) << 3];
            }
#pragma unroll
            for (int mi = 0; mi < 4; mi++)
#pragma unroll
                for (int ni = 0; ni < 4; ni++)
                    acc[mi][ni] = mfma16(af[mi], bfr[ni], acc[mi][ni]);
        }
        __syncthreads();
    }
#pragma unroll
    for (int mi = 0; mi < 4; mi++)
#pragma unroll
        for (int ni = 0; ni < 4; ni++)
#pragma unroll
            for (int r = 0; r < 4; r++)
                stf(&C[(m0 + wr * 64 + mi * 16 + (lane >> 4) * 4 + r) * (long)N +
                       n0 + wc * 64 + ni * 16 + (lane & 15)], acc[mi][ni][r]);
}

// ---------------- dt = softplus(inputs @ Wdt + bias) ----------------
__global__ void dt_kernel(const float* __restrict__ inp, const float* __restrict__ Wdt,
                          const float* __restrict__ dt_bias, float* __restrict__ dtb) {
    __shared__ float wlds[DM * NH];  // 16 KB
    int t = threadIdx.x;
#pragma unroll
    for (int i = 0; i < 16; i++) wlds[t + i * 256] = Wdt[t + i * 256];
    __syncthreads();
    int idx = blockIdx.x * 256 + t;
    int h = idx & 7;
    long row = idx >> 3;
    const float* ir = inp + row * DM;
    float acc = 0.f;
    for (int k = 0; k < DM; k += 4) {
        float4 a = *(const float4*)&ir[k];
        acc += a.x * wlds[k * 8 + h] + a.y * wlds[(k + 1) * 8 + h]
             + a.z * wlds[(k + 2) * 8 + h] + a.w * wlds[(k + 3) * 8 + h];
    }
    acc += dt_bias[h];
    float sp = acc > 20.f ? acc : log1pf(expf(acc));
    dtb[idx] = sp;
}

// ---------------- conv(4) + silu + split + x*dt (8 ch / thread) ----------------
__global__ void conv_silu_split(const bf16* __restrict__ xbc, const float* __restrict__ ck,
                                const float* __restrict__ dtb, bf16* __restrict__ xdt,
                                bf16* __restrict__ bm, bf16* __restrict__ cm) {
    long idx = (long)blockIdx.x * 256 + threadIdx.x;
    if (idx >= (long)MROWS * CONVD / 8) return;
    long e0 = idx * 8;
    int ch = (int)(e0 % CONVD);
    long bl = e0 / CONVD;
    int l = (int)(bl % LL);
    float acc[8] = {};
#pragma unroll
    for (int k = 0; k < DCONV; k++) {
        int ls = l - 3 + k;
        if (ls >= 0) {
            bf16 v[8];
            *(uint4*)v = *(const uint4*)&xbc[(bl - l + ls) * CONVD + ch];
            float4 c0 = *(const float4*)&ck[k * CONVD + ch];
            float4 c1 = *(const float4*)&ck[k * CONVD + ch + 4];
            acc[0] += __bfloat162float(v[0]) * c0.x;
            acc[1] += __bfloat162float(v[1]) * c0.y;
            acc[2] += __bfloat162float(v[2]) * c0.z;
            acc[3] += __bfloat162float(v[3]) * c0.w;
            acc[4] += __bfloat162float(v[4]) * c1.x;
            acc[5] += __bfloat162float(v[5]) * c1.y;
            acc[6] += __bfloat162float(v[6]) * c1.z;
            acc[7] += __bfloat162float(v[7]) * c1.w;
        }
    }
    bf16 o[8];
    if (ch < DI) {
        float dt = dtb[bl * NH + (ch >> 8)];
#pragma unroll
        for (int j = 0; j < 8; j++) {
            float s = acc[j] / (1.f + expf(-acc[j]));
            o[j] = __float2bfloat16(s * dt);
        }
        *(uint4*)&xdt[bl * DI + ch] = *(uint4*)o;
    } else {
#pragma unroll
        for (int j = 0; j < 8; j++) {
            float s = acc[j] / (1.f + expf(-acc[j]));
            o[j] = __float2bfloat16(s);
        }
        if (ch < DI + DS) *(uint4*)&bm[bl * DS + (ch - DI)] = *(uint4*)o;
        else              *(uint4*)&cm[bl * DS + (ch - DI - DS)] = *(uint4*)o;
    }
}

// ---------------- per-(b,h,c) cumsum of a*dt ----------------
__global__ void cumsum_kernel(const float* __restrict__ dtb, const float* __restrict__ a_log,
                              float* __restrict__ cumA, float* __restrict__ csum) {
    int t = blockIdx.x * 256 + threadIdx.x;  // t = b*128 + h*16 + c
    if (t >= BB * NH * NC) return;
    int c = t & 15, h = (t >> 4) & 7, b = t >> 7;
    float a = -expf(a_log[h]);
    long base_l = (long)b * LL + (long)c * CHK;
    float s = 0.f;
    long obase = (long)t * CHK;
    for (int i = 0; i < CHK; i++) {
        s += a * dtb[(base_l + i) * NH + h];
        cumA[obase + i] = s;
    }
    csum[t] = s;
}

// ---------------- states via MFMA: st[p][n] = sum_l x[l,p]*b[l,n]*dec[l] ----------------
__global__ __launch_bounds__(256) void states_mfma(
        const bf16* __restrict__ bmat, const bf16* __restrict__ xdtT,
        const float* __restrict__ cumA, const float* __restrict__ csum,
        bf16* __restrict__ st) {
    __shared__ __align__(16) bf16 XT[256][72];  // p rows, l cols (block-XOR key p&7)
    __shared__ __align__(16) bf16 BT[64][72];   // n rows, l cols (block-XOR key n&7)
    const int z = blockIdx.x;  // b*128 + c*8 + h
    const int h = z & 7, c = (z >> 3) & 15, b = z >> 7;
    const long blr = (long)b * LL + (long)c * CHK;
    const int bhc = (b * NH + h) * NC + c;
    const float A = csum[bhc];
    const int t = threadIdx.x, lane = t & 63, w = t >> 6;
    const bf16* xrow = xdtT + ((long)b * DI + h * HD) * LL + c * CHK;
    f4 acc[4][4];
#pragma unroll
    for (int mi = 0; mi < 4; mi++)
#pragma unroll
        for (int ni = 0; ni < 4; ni++) acc[mi][ni] = (f4){0.f, 0.f, 0.f, 0.f};

    for (int lt = 0; lt < 4; lt++) {
        const int l0 = lt * 64;
        // bdec^T scatter (small) with decay applied along K
#pragma unroll
        for (int i = 0; i < 2; i++) {
            int u = t + i * 256; int l = u >> 3, n8 = (u & 7) * 8;
            bf16 v[8];
            *(uint4*)v = *(const uint4*)&bmat[(blr + l0 + l) * DS + n8];
            float d = expf(A - cumA[(long)bhc * CHK + l0 + l]);
#pragma unroll
            for (int j = 0; j < 8; j++) {
                int n = n8 + j;
                BT[n][l ^ ((n & 7) << 3)] = __float2bfloat16(__bfloat162float(v[j]) * d);
            }
        }
        // x^T tile: straight uint4 from xdtT with source-block XOR
#pragma unroll
        for (int i = 0; i < 8; i++) {
            int u = t + i * 256; int pp = u >> 3, s8 = u & 7;
            *(uint4*)&XT[pp][s8 * 8] =
                *(const uint4*)&xrow[(long)pp * LL + l0 + ((s8 ^ (pp & 7)) << 3)];
        }
        __syncthreads();
#pragma unroll
        for (int ks = 0; ks < 2; ks++) {
            int col = ks * 32 + (lane >> 4) * 8;
            s8 af[4], bx[4];
#pragma unroll
            for (int mi = 0; mi < 4; mi++) {
                int n = mi * 16 + (lane & 15);
                af[mi] = *(const s8*)&BT[n][col ^ ((n & 7) << 3)];
            }
#pragma unroll
            for (int ni = 0; ni < 4; ni++) {
                int p = w * 64 + ni * 16 + (lane & 15);
                bx[ni] = *(const s8*)&XT[p][col ^ ((p & 7) << 3)];
            }
#pragma unroll
            for (int mi = 0; mi < 4; mi++)
#pragma unroll
                for (int ni = 0; ni < 4; ni++)
                    acc[mi][ni] = mfma16(af[mi], bx[ni], acc[mi][ni]);
        }
        __syncthreads();
    }
    // D rows = n, cols = p; write st[p][n] bf16, 8B along n
    bf16* so = st + (long)z * (HD * DS);
#pragma unroll
    for (int mi = 0; mi < 4; mi++)
#pragma unroll
        for (int ni = 0; ni < 4; ni++) {
            int p = w * 64 + ni * 16 + (lane & 15);
            int n0 = mi * 16 + (lane >> 4) * 4;
            bf16 vv[4];
#pragma unroll
            for (int r = 0; r < 4; r++) vv[r] = __float2bfloat16(acc[mi][ni][r]);
            *(uint2*)&so[p * 64 + n0] = *(uint2*)vv;
        }
}

// ---------------- serial chunk scan (in place, bf16, f32 accum in regs) ----------------
__global__ void scan_kernel(bf16* __restrict__ st, const float* __restrict__ csum) {
    long idx = (long)blockIdx.x * 256 + threadIdx.x;
    int pn = (int)(idx & 16383);
    int h = (int)((idx >> 14) & 7);
    int b = (int)(idx >> 17);
    float S = 0.f;
    for (int c = 0; c < NC; c++) {
        long si = (((long)(b * NC + c) * NH + h) * (HD * DS)) + pn;
        float chunk = __bfloat162float(st[si]);
        st[si] = __float2bfloat16(S);
        S = S * expf(csum[(b * NH + h) * NC + c]) + chunk;
    }
}

// ---------------- fused SSD y via MFMA ----------------
__global__ __launch_bounds__(256) void ssd_y_mfma(
        const bf16* __restrict__ bmat, const bf16* __restrict__ cmat,
        const bf16* __restrict__ xdtT, const bf16* __restrict__ st,
        const float* __restrict__ cumA, bf16* __restrict__ y) {
    __shared__ __align__(16) bf16 cT[64][72];     // c rows l, cols n
    __shared__ __align__(16) bf16 bWt[64][72];    // phase 1: b rows s; phase 2: W rows l
    __shared__ __align__(16) bf16 XTt[256][72];   // X^T rows p (block-XOR key p&7); Y scratch
    __shared__ float cumL[64], cumS[64];

    const int t = threadIdx.x, lane = t & 63, w = t >> 6;
    // XCD-aware swizzle: 4 lt-blocks of one chunk land on the same XCD (L2 reuse)
    const int bid0 = blockIdx.x;
    const int bid = (bid0 & 7) * 256 + (bid0 >> 3);   // grid = 2048
    const int zt = bid >> 2, lt = bid & 3;
    const int h = zt & 7, c = (zt >> 3) & 15, b = zt >> 7;
    const long blr = (long)b * LL + (long)c * CHK;
    const int bhc = (b * NH + h) * NC + c;
    const int l0 = lt * 64;
    const bf16* xrow = xdtT + ((long)b * DI + h * HD) * LL + c * CHK;

#pragma unroll
    for (int i = 0; i < 2; i++) {
        int u = t + i * 256; int row = u >> 3, n8 = (u & 7) * 8;
        *(uint4*)&cT[row][n8] = *(const uint4*)&cmat[(blr + l0 + row) * DS + n8];
    }
    if (t < 64) cumL[t] = cumA[(long)bhc * CHK + l0 + t];

    f4 acc[4][4];
#pragma unroll
    for (int mi = 0; mi < 4; mi++)
#pragma unroll
        for (int ni = 0; ni < 4; ni++) acc[mi][ni] = (f4){0.f, 0.f, 0.f, 0.f};
    __syncthreads();

    for (int stile = 0; stile <= lt; stile++) {
        const int s0 = stile * 64;
#pragma unroll
        for (int i = 0; i < 2; i++) {
            int u = t + i * 256; int row = u >> 3, n8 = (u & 7) * 8;
            *(uint4*)&bWt[row][n8] = *(const uint4*)&bmat[(blr + s0 + row) * DS + n8];
        }
        if (t < 64) cumS[t] = cumA[(long)bhc * CHK + s0 + t];
        // X^T tile via uint4 + source-block XOR
#pragma unroll
        for (int i = 0; i < 8; i++) {
            int u = t + i * 256; int pp = u >> 3, s8 = u & 7;
            *(uint4*)&XTt[pp][s8 * 8] =
                *(const uint4*)&xrow[(long)pp * LL + s0 + ((s8 ^ (pp & 7)) << 3)];
        }
        __syncthreads();

        // W-gemm: wave w computes W rows [w*16, w*16+16) x 64 s, K=64 (n)
        f4 wacc[4];
#pragma unroll
        for (int ni = 0; ni < 4; ni++) wacc[ni] = (f4){0.f, 0.f, 0.f, 0.f};
#pragma unroll
        for (int ks = 0; ks < 2; ks++) {
            s8 af = *(const s8*)&cT[w * 16 + (lane & 15)][ks * 32 + (lane >> 4) * 8];
#pragma unroll
            for (int ni = 0; ni < 4; ni++) {
                s8 bfr = *(const s8*)&bWt[ni * 16 + (lane & 15)][ks * 32 + (lane >> 4) * 8];
                wacc[ni] = mfma16(af, bfr, wacc[ni]);
            }
        }
        __syncthreads();

        // epilogue: decay+mask, write W (bf16) into bWt
#pragma unroll
        for (int ni = 0; ni < 4; ni++) {
            int s_idx = ni * 16 + (lane & 15);
#pragma unroll
            for (int r = 0; r < 4; r++) {
                int l_loc = w * 16 + (lane >> 4) * 4 + r;
                bool valid = (stile < lt) || (l_loc >= s_idx);
                float val = valid ? wacc[ni][r] * expf(cumL[l_loc] - cumS[s_idx]) : 0.f;
                bWt[l_loc][s_idx] = __float2bfloat16(val);
            }
        }
        __syncthreads();

        // Y-gemm: wave w: 64 l x p-range [w*64, w*64+64), K=64 (s)
#pragma unroll
        for (int ks = 0; ks < 2; ks++) {
            int k8 = ks * 4 + (lane >> 4);
            s8 aw[4], bx[4];
#pragma unroll
            for (int mi = 0; mi < 4; mi++)
                aw[mi] = *(const s8*)&bWt[mi * 16 + (lane & 15)][k8 * 8];
#pragma unroll
            for (int ni = 0; ni < 4; ni++) {
                int p = w * 64 + ni * 16 + (lane & 15);
                bx[ni] = *(const s8*)&XTt[p][(k8 ^ (p & 7)) << 3];
            }
#pragma unroll
            for (int mi = 0; mi < 4; mi++)
#pragma unroll
                for (int ni = 0; ni < 4; ni++)
                    acc[mi][ni] = mfma16(aw[mi], bx[ni], acc[mi][ni]);
        }
        __syncthreads();
    }

    // ---- inter-chunk state tile: W = c*exp(cumL), X = st^T (bf16 already) ----
#pragma unroll
    for (int i = 0; i < 16; i++) {
        int u = t + i * 256; int l = u >> 6, n = u & 63;
        bWt[l][n] = __float2bfloat16(__bfloat162float(cT[l][n]) * expf(cumL[l]));
    }
    {
        const bf16* sp = st + (long)zt * (HD * DS) + t * DS;
#pragma unroll
        for (int g = 0; g < 8; g++)
            *(uint4*)&XTt[t][g * 8] = *(const uint4*)&sp[(g ^ (t & 7)) << 3];
    }
    __syncthreads();
#pragma unroll
    for (int ks = 0; ks < 2; ks++) {
        int k8 = ks * 4 + (lane >> 4);
        s8 aw[4], bx[4];
#pragma unroll
        for (int mi = 0; mi < 4; mi++)
            aw[mi] = *(const s8*)&bWt[mi * 16 + (lane & 15)][k8 * 8];
#pragma unroll
        for (int ni = 0; ni < 4; ni++) {
            int p = w * 64 + ni * 16 + (lane & 15);
            bx[ni] = *(const s8*)&XTt[p][(k8 ^ (p & 7)) << 3];
        }
#pragma unroll
        for (int mi = 0; mi < 4; mi++)
#pragma unroll
            for (int ni = 0; ni < 4; ni++)
                acc[mi][ni] = mfma16(aw[mi], bx[ni], acc[mi][ni]);
    }
    __syncthreads();

    // ---- epilogue: frags -> LDS -> coalesced global ----
    bf16* Yl = (bf16*)XTt;
#pragma unroll
    for (int mi = 0; mi < 4; mi++)
#pragma unroll
        for (int ni = 0; ni < 4; ni++)
#pragma unroll
            for (int r = 0; r < 4; r++)
                Yl[(mi * 16 + (lane >> 4) * 4 + r) * 256 + w * 64 + ni * 16 + (lane & 15)] =
                    __float2bfloat16(acc[mi][ni][r]);
    __syncthreads();
#pragma unroll
    for (int i = 0; i < 8; i++) {
        int u = t + i * 256; int l = u >> 5, p8 = u & 31;
        *(uint4*)&y[(blr + l0 + l) * DI + h * HD + p8 * 8] = *(uint4*)&Yl[l * 256 + p8 * 8];
    }
}

// ---------------- gate (silu(z)) + RMSNorm, vectorized ----------------
__global__ void gatenorm_kernel(const bf16* __restrict__ y, const bf16* __restrict__ z,
                                const float* __restrict__ gamma, bf16* __restrict__ out) {
    int row = blockIdx.x;
    int tid = threadIdx.x;
    int d0 = tid * 8;
    bf16 yv[8], zv[8];
    *(uint4*)yv = *(const uint4*)&y[(long)row * DI + d0];
    *(uint4*)zv = *(const uint4*)&z[(long)row * DI + d0];
    float g[8];
    float ss = 0.f;
#pragma unroll
    for (int i = 0; i < 8; i++) {
        float zf = __bfloat162float(zv[i]);
        float gate = zf / (1.f + expf(-zf));
        float v = __bfloat162float(yv[i]) * gate;
        g[i] = v;
        ss += v * v;
    }
#pragma unroll
    for (int off = 32; off > 0; off >>= 1) ss += __shfl_down(ss, off);
    __shared__ float red[4];
    if ((tid & 63) == 0) red[tid >> 6] = ss;
    __syncthreads();
    float tot = red[0] + red[1] + red[2] + red[3];
    float scale = rsqrtf(tot / (float)DI + 1e-5f);
    float4 g0 = *(const float4*)&gamma[d0];
    float4 g1 = *(const float4*)&gamma[d0 + 4];
    bf16 o[8];
    o[0] = __float2bfloat16(g[0] * scale * g0.x);
    o[1] = __float2bfloat16(g[1] * scale * g0.y);
    o[2] = __float2bfloat16(g[2] * scale * g0.z);
    o[3] = __float2bfloat16(g[3] * scale * g0.w);
    o[4] = __float2bfloat16(g[4] * scale * g1.x);
    o[5] = __float2bfloat16(g[5] * scale * g1.y);
    o[6] = __float2bfloat16(g[6] * scale * g1.z);
    o[7] = __float2bfloat16(g[7] * scale * g1.w);
    *(uint4*)&out[(long)row * DI + d0] = *(uint4*)o;
}

extern "C" void kernel_launch(void* const* d_in, const int* in_sizes, int n_in,
                              void* d_out, int out_size, void* d_ws, size_t ws_size,
                              hipStream_t stream) {
    const float* inputs = (const float*)d_in[0];
    const float* Wz = (const float*)d_in[1];
    const float* Wxbc = (const float*)d_in[2];
    const float* Wdt = (const float*)d_in[3];
    const float* conv_kernel = (const float*)d_in[4];
    const float* dt_bias = (const float*)d_in[5];
    const float* a_log = (const float*)d_in[6];
    const float* gamma = (const float*)d_in[7];
    const float* Wout = (const float*)d_in[8];
    float* out = (float*)d_out;

    // ---- workspace layout (~223 MiB) ----
    char* p = (char*)d_ws;
    float* dtb = (float*)p;      p += (long)MROWS * NH * 4;
    float* cumA = (float*)p;     p += (long)MROWS * NH * 4;
    float* csum = (float*)p;     p += 512 * 4;
    bf16* WzT = (bf16*)p;        p += (long)DI * DM * 2;
    bf16* WxbcT = (bf16*)p;      p += (long)CONVD * DM * 2;
    bf16* WoutT = (bf16*)p;      p += (long)DM * DI * 2;
    bf16* bmat = (bf16*)p;       p += (long)MROWS * DS * 2;
    bf16* cmat = (bf16*)p;       p += (long)MROWS * DS * 2;
    bf16* inA = (bf16*)p;        p += (long)MROWS * DM * 2;   // 16.8 MB; -> st (bf16, same size)
    bf16* regA = (bf16*)p;       p += (long)MROWS * CONVD * 2; // xbc_raw -> xdtT
    bf16* regB = (bf16*)p;       p += (long)MROWS * DI * 2;    // xdt -> z -> ynorm
    bf16* regC = (bf16*)p;       p += (long)MROWS * DI * 2;    // y
    bf16* st = inA;              // aliased after z-GEMM

    // 1. casts / weight transposes
    cast_bf16_kernel<<<MROWS * DM / 8 / 256, 256, 0, stream>>>(inputs, inA);
    tcast_kernel<<<dim3(DI / 64, DM / 64), 256, 0, stream>>>(Wz, WzT, DM, DI);
    tcast_kernel<<<dim3(CONVD / 64, DM / 64), 256, 0, stream>>>(Wxbc, WxbcT, DM, CONVD);
    tcast_kernel<<<dim3(DM / 64, DI / 64), 256, 0, stream>>>(Wout, WoutT, DI, DM);
    // 2. xbc = inA @ Wxbc
    mfma_gemm<bf16><<<dim3(CONVD / 128, MROWS / 128), 256, 0, stream>>>(inA, WxbcT, regA, CONVD, DM);
    // 3. dt
    dt_kernel<<<MROWS * NH / 256, 256, 0, stream>>>(inputs, Wdt, dt_bias, dtb);
    // 4. conv + silu + split + x*dt  (xdt into regB)
    long convtot = (long)MROWS * CONVD / 8;
    conv_silu_split<<<(unsigned)((convtot + 255) / 256), 256, 0, stream>>>(regA, conv_kernel, dtb, regB, bmat, cmat);
    // 5. x^T  (xdtT into regA over dead xbc)
    transpose_x<<<BB * (LL / 64) * (DI / 64), 256, 0, stream>>>(regB, regA);
    // 6. z = inA @ Wz (into regB over dead xdt)
    mfma_gemm<bf16><<<dim3(DI / 128, MROWS / 128), 256, 0, stream>>>(inA, WzT, regB, DI, DM);
    // 7. cumsum
    cumsum_kernel<<<2, 256, 0, stream>>>(dtb, a_log, cumA, csum);
    // 8. per-chunk states (MFMA, reads xdtT) -> st (bf16, over dead inA)
    states_mfma<<<BB * NC * NH, 256, 0, stream>>>(bmat, regA, cumA, csum, st);
    // 9. chunk scan (in place)
    scan_kernel<<<BB * NH * HD * DS / 256, 256, 0, stream>>>(st, csum);
    // 10. fused SSD y (MFMA) -> regC
    ssd_y_mfma<<<BB * NC * NH * 4, 256, 0, stream>>>(bmat, cmat, regA, st, cumA, regC);
    // 11. gate + rmsnorm (ynorm in-place over z)
    gatenorm_kernel<<<MROWS, 256, 0, stream>>>(regC, regB, gamma, regB);
    // 12. out = ynorm @ Wout
    mfma_gemm<float><<<dim3(DM / 128, MROWS / 128), 256, 0, stream>>>(regB, WoutT, out, DM, DI);
}

// Round 6
// 387.649 us; speedup vs baseline: 14.8311x; 1.1559x over previous
//
#include <hip/hip_runtime.h>
#include <hip/hip_bf16.h>

// Mamba2 block forward. B=4 L=4096 D_MODEL=512 D_INNER=2048 H=8 P=256 N=64
// CHUNK=256 C=16 CONV_DIM=2176.
// Round 6: ssd_y v2 (no pads, uniform XOR swizzle, 3 blocks/CU, __expf,
// setprio); merged z+xbc GEMM -> zxbc[16384][4224]; conv_x writes xdtT
// directly (transpose_x deleted); y/ynorm live inside zxbc. ~223 MiB ws.

#define BB 4
#define LL 4096
#define DM 512
#define DI 2048
#define NH 8
#define HD 256
#define DS 64
#define DCONV 4
#define CHK 256
#define NC 16
#define CONVD 2176
#define MROWS (BB*LL)   // 16384
#define ZXW (DI + CONVD) // 4224

typedef __hip_bfloat16 bf16;
typedef short s8 __attribute__((ext_vector_type(8)));   // 8 bf16 (4 VGPRs)
typedef float f4 __attribute__((ext_vector_type(4)));   // MFMA acc

__device__ __forceinline__ f4 mfma16(s8 a, s8 b, f4 c) {
    return __builtin_amdgcn_mfma_f32_16x16x32_bf16(a, b, c, 0, 0, 0);
}

__device__ __forceinline__ void gload16(const bf16* g, bf16* l) {
    __builtin_amdgcn_global_load_lds(
        (const __attribute__((address_space(1))) void*)g,
        (__attribute__((address_space(3))) void*)l, 16, 0, 0);
}

__device__ __forceinline__ float ldf(const float* p) { return *p; }
__device__ __forceinline__ float ldf(const bf16* p) { return __bfloat162float(*p); }
__device__ __forceinline__ void stf(float* p, float v) { *p = v; }
__device__ __forceinline__ void stf(bf16* p, float v) { *p = __float2bfloat16(v); }

// ---------------- f32 -> bf16 cast (8/thread) ----------------
__global__ void cast_bf16_kernel(const float* __restrict__ in, bf16* __restrict__ out) {
    long i8 = ((long)blockIdx.x * 256 + threadIdx.x) * 8;
    float4 a = *(const float4*)&in[i8];
    float4 b = *(const float4*)&in[i8 + 4];
    bf16 v[8];
    v[0] = __float2bfloat16(a.x); v[1] = __float2bfloat16(a.y);
    v[2] = __float2bfloat16(a.z); v[3] = __float2bfloat16(a.w);
    v[4] = __float2bfloat16(b.x); v[5] = __float2bfloat16(b.y);
    v[6] = __float2bfloat16(b.z); v[7] = __float2bfloat16(b.w);
    *(uint4*)&out[i8] = *(uint4*)v;
}

// ---------------- f32 [K][N] -> bf16 [N][K] transpose-cast (weights) ----------------
__global__ void tcast_kernel(const float* __restrict__ in, bf16* __restrict__ out,
                             int K, int N) {
    __shared__ float tile[64][65];
    int t = threadIdx.x;
    int n0 = blockIdx.x * 64, k0 = blockIdx.y * 64;
#pragma unroll
    for (int i = 0; i < 16; i++) {
        int u = t + i * 256; int kr = u >> 6, nc = u & 63;
        tile[kr][nc] = in[(long)(k0 + kr) * N + n0 + nc];
    }
    __syncthreads();
#pragma unroll
    for (int i = 0; i < 16; i++) {
        int u = t + i * 256; int nr = u >> 6, kc = u & 63;
        out[(long)(n0 + nr) * K + k0 + kc] = __float2bfloat16(tile[kc][nr]);
    }
}

// ---------------- bf16 MFMA GEMM via global_load_lds + src-XOR swizzle ----------------
// C[M][N] = A[M][K] @ BT[N][K]^T. 128x128 tile, BK=64, 4 waves.
template <typename TC>
__global__ __launch_bounds__(256) void mfma_gemm(const bf16* __restrict__ A,
                                                 const bf16* __restrict__ BT,
                                                 TC* __restrict__ C, int N, int K,
                                                 int lda, int ldc) {
    __shared__ __align__(16) bf16 At[128][64];
    __shared__ __align__(16) bf16 Bt[128][64];
    const int t = threadIdx.x, lane = t & 63, w = t >> 6;
    const int wr = w >> 1, wc = w & 1;
    const long m0 = (long)blockIdx.y * 128;
    const int n0 = blockIdx.x * 128;
    const int lrow = lane >> 3, lblk = lane & 7;
    f4 acc[4][4];
#pragma unroll
    for (int mi = 0; mi < 4; mi++)
#pragma unroll
        for (int ni = 0; ni < 4; ni++) acc[mi][ni] = (f4){0.f, 0.f, 0.f, 0.f};

    for (int k0 = 0; k0 < K; k0 += 64) {
#pragma unroll
        for (int i = 0; i < 4; i++) {
            int rbase = w * 32 + i * 8;
            int row = rbase + lrow;
            int kb = (lblk ^ (row & 7)) << 3;   // source k-block, pre-swizzled
            gload16(&A[(m0 + row) * (long)lda + k0 + kb], &At[rbase][0]);
            gload16(&BT[((long)n0 + row) * K + k0 + kb], &Bt[rbase][0]);
        }
        __syncthreads();
        __builtin_amdgcn_s_setprio(1);
#pragma unroll
        for (int ks = 0; ks < 2; ks++) {
            int k8 = ks * 4 + (lane >> 4);
            s8 af[4], bfr[4];
#pragma unroll
            for (int mi = 0; mi < 4; mi++) {
                int row = wr * 64 + mi * 16 + (lane & 15);
                af[mi] = *(const s8*)&At[row][(k8 ^ (row & 7)) << 3];
            }
#pragma unroll
            for (int ni = 0; ni < 4; ni++) {
                int row = wc * 64 + ni * 16 + (lane & 15);
                bfr[ni] = *(const s8*)&Bt[row][(k8 ^ (row & 7)) << 3];
            }
#pragma unroll
            for (int mi = 0; mi < 4; mi++)
#pragma unroll
                for (int ni = 0; ni < 4; ni++)
                    acc[mi][ni] = mfma16(af[mi], bfr[ni], acc[mi][ni]);
        }
        __builtin_amdgcn_s_setprio(0);
        __syncthreads();
    }
#pragma unroll
    for (int mi = 0; mi < 4; mi++)
#pragma unroll
        for (int ni = 0; ni < 4; ni++)
#pragma unroll
            for (int r = 0; r < 4; r++)
                stf(&C[(m0 + wr * 64 + mi * 16 + (lane >> 4) * 4 + r) * (long)ldc +
                       n0 + wc * 64 + ni * 16 + (lane & 15)], acc[mi][ni][r]);
}

// ---------------- dt = softplus(inputs @ Wdt + bias) ----------------
__global__ void dt_kernel(const float* __restrict__ inp, const float* __restrict__ Wdt,
                          const float* __restrict__ dt_bias, float* __restrict__ dtb) {
    __shared__ float wlds[DM * NH];  // 16 KB
    int t = threadIdx.x;
#pragma unroll
    for (int i = 0; i < 16; i++) wlds[t + i * 256] = Wdt[t + i * 256];
    __syncthreads();
    int idx = blockIdx.x * 256 + t;
    int h = idx & 7;
    long row = idx >> 3;
    const float* ir = inp + row * DM;
    float acc = 0.f;
    for (int k = 0; k < DM; k += 4) {
        float4 a = *(const float4*)&ir[k];
        acc += a.x * wlds[k * 8 + h] + a.y * wlds[(k + 1) * 8 + h]
             + a.z * wlds[(k + 2) * 8 + h] + a.w * wlds[(k + 3) * 8 + h];
    }
    acc += dt_bias[h];
    float sp = acc > 20.f ? acc : log1pf(expf(acc));
    dtb[idx] = sp;
}

// ---------------- conv_x: conv(4)+silu+*dt over x channels, writes xdtT ----------------
// block: b*(64*32) + lt*32 + ct. 64 l-rows x 64 channels; output transposed.
__global__ __launch_bounds__(256) void conv_x(const bf16* __restrict__ zxbc,
                                              const float* __restrict__ ck,
                                              const float* __restrict__ dtb,
                                              bf16* __restrict__ xdtT) {
    __shared__ __align__(16) bf16 in_lds[67][72];
    __shared__ __align__(16) bf16 out_lds[64][64];
    __shared__ float dts[64];
    const int bid = blockIdx.x;
    const int ct = bid & 31, lt = (bid >> 5) & 63, b = bid >> 11;
    const int t = threadIdx.x;
    const int l0 = lt * 64;
    const long brow = (long)b * LL;
    const int h = ct >> 2;

    // stage input rows [l0-3, l0+63] x 64 ch (x part = zxbc cols 2048+ct*64..)
#pragma unroll
    for (int i = 0; i < 3; i++) {
        int u = t + i * 256;
        if (u < 536) {
            int r = u >> 3, c8 = (u & 7) * 8;
            int gl = l0 - 3 + r;
            uint4 v = (gl >= 0)
                ? *(const uint4*)&zxbc[(brow + gl) * ZXW + DI + ct * 64 + c8]
                : (uint4){0, 0, 0, 0};
            *(uint4*)&in_lds[r][c8] = v;
        }
    }
    if (t < 64) dts[t] = dtb[(brow + l0 + t) * NH + h];
    __syncthreads();

    // compute: thread -> ch = t&63, l range [w*16, w*16+16)
    const int ch = t & 63, w = t >> 6;
    const int gch = ct * 64 + ch;
    float k0 = ck[0 * CONVD + gch], k1 = ck[1 * CONVD + gch];
    float k2 = ck[2 * CONVD + gch], k3 = ck[3 * CONVD + gch];
    float w0 = __bfloat162float(in_lds[w * 16 + 0][ch]);
    float w1 = __bfloat162float(in_lds[w * 16 + 1][ch]);
    float w2 = __bfloat162float(in_lds[w * 16 + 2][ch]);
    bf16 o[16];
#pragma unroll
    for (int i = 0; i < 16; i++) {
        float w3 = __bfloat162float(in_lds[w * 16 + i + 3][ch]);
        float v = w0 * k0 + w1 * k1 + w2 * k2 + w3 * k3;
        float s = v / (1.f + __expf(-v));
        o[i] = __float2bfloat16(s * dts[w * 16 + i]);
        w0 = w1; w1 = w2; w2 = w3;
    }
    // out_lds[ch][l], logical block stored at phys blk^(ch&7)
#pragma unroll
    for (int j = 0; j < 2; j++) {
        int blk = w * 2 + j;
        *(uint4*)&out_lds[ch][((blk ^ (ch & 7)) << 3)] = *(uint4*)&o[j * 8];
    }
    __syncthreads();
    // write out: 64 ch rows x 64 l, coalesced 128B per row
#pragma unroll
    for (int i = 0; i < 2; i++) {
        int u = t + i * 256;
        int chr = u >> 3, l8 = u & 7;
        uint4 v = *(const uint4*)&out_lds[chr][((l8 ^ (chr & 7)) << 3)];
        *(uint4*)&xdtT[((long)b * DI + ct * 64 + chr) * LL + l0 + l8 * 8] = v;
    }
}

// ---------------- conv_bc: conv+silu for b/c channels (zxbc cols 4096..4223) ----------------
__global__ void conv_bc(const bf16* __restrict__ zxbc, const float* __restrict__ ck,
                        bf16* __restrict__ bm, bf16* __restrict__ cm) {
    long idx = (long)blockIdx.x * 256 + threadIdx.x;   // MROWS*128/8
    if (idx >= (long)MROWS * 128 / 8) return;
    long e0 = idx * 8;
    int ch = (int)(e0 & 127);
    long bl = e0 >> 7;
    int l = (int)(bl & (LL - 1));
    float acc[8] = {};
#pragma unroll
    for (int k = 0; k < DCONV; k++) {
        int ls = l - 3 + k;
        if (ls >= 0) {
            bf16 v[8];
            *(uint4*)v = *(const uint4*)&zxbc[(bl - l + ls) * ZXW + 2 * DI + ch];
            float4 c0 = *(const float4*)&ck[k * CONVD + DI + ch];
            float4 c1 = *(const float4*)&ck[k * CONVD + DI + ch + 4];
            acc[0] += __bfloat162float(v[0]) * c0.x;
            acc[1] += __bfloat162float(v[1]) * c0.y;
            acc[2] += __bfloat162float(v[2]) * c0.z;
            acc[3] += __bfloat162float(v[3]) * c0.w;
            acc[4] += __bfloat162float(v[4]) * c1.x;
            acc[5] += __bfloat162float(v[5]) * c1.y;
            acc[6] += __bfloat162float(v[6]) * c1.z;
            acc[7] += __bfloat162float(v[7]) * c1.w;
        }
    }
    bf16 o[8];
#pragma unroll
    for (int j = 0; j < 8; j++) {
        float s = acc[j] / (1.f + __expf(-acc[j]));
        o[j] = __float2bfloat16(s);
    }
    if (ch < DS) *(uint4*)&bm[bl * DS + ch] = *(uint4*)o;
    else         *(uint4*)&cm[bl * DS + (ch - DS)] = *(uint4*)o;
}

// ---------------- per-(b,h,c) cumsum of a*dt ----------------
__global__ void cumsum_kernel(const float* __restrict__ dtb, const float* __restrict__ a_log,
                              float* __restrict__ cumA, float* __restrict__ csum) {
    int t = blockIdx.x * 256 + threadIdx.x;  // t = b*128 + h*16 + c
    if (t >= BB * NH * NC) return;
    int c = t & 15, h = (t >> 4) & 7, b = t >> 7;
    float a = -expf(a_log[h]);
    long base_l = (long)b * LL + (long)c * CHK;
    float s = 0.f;
    long obase = (long)t * CHK;
    for (int i = 0; i < CHK; i++) {
        s += a * dtb[(base_l + i) * NH + h];
        cumA[obase + i] = s;
    }
    csum[t] = s;
}

// ---------------- states via MFMA: st[p][n] = sum_l x[l,p]*b[l,n]*dec[l] ----------------
__global__ __launch_bounds__(256) void states_mfma(
        const bf16* __restrict__ bmat, const bf16* __restrict__ xdtT,
        const float* __restrict__ cumA, const float* __restrict__ csum,
        bf16* __restrict__ st) {
    __shared__ __align__(16) bf16 XT[256][72];  // p rows, l cols (block-XOR key p&7)
    __shared__ __align__(16) bf16 BT[64][72];   // n rows, l cols (block-XOR key n&7)
    const int z = blockIdx.x;  // b*128 + c*8 + h
    const int h = z & 7, c = (z >> 3) & 15, b = z >> 7;
    const long blr = (long)b * LL + (long)c * CHK;
    const int bhc = (b * NH + h) * NC + c;
    const float A = csum[bhc];
    const int t = threadIdx.x, lane = t & 63, w = t >> 6;
    const bf16* xrow = xdtT + ((long)b * DI + h * HD) * LL + c * CHK;
    f4 acc[4][4];
#pragma unroll
    for (int mi = 0; mi < 4; mi++)
#pragma unroll
        for (int ni = 0; ni < 4; ni++) acc[mi][ni] = (f4){0.f, 0.f, 0.f, 0.f};

    for (int lt = 0; lt < 4; lt++) {
        const int l0 = lt * 64;
#pragma unroll
        for (int i = 0; i < 2; i++) {
            int u = t + i * 256; int l = u >> 3, n8 = (u & 7) * 8;
            bf16 v[8];
            *(uint4*)v = *(const uint4*)&bmat[(blr + l0 + l) * DS + n8];
            float d = __expf(A - cumA[(long)bhc * CHK + l0 + l]);
#pragma unroll
            for (int j = 0; j < 8; j++) {
                int n = n8 + j;
                BT[n][l ^ ((n & 7) << 3)] = __float2bfloat16(__bfloat162float(v[j]) * d);
            }
        }
#pragma unroll
        for (int i = 0; i < 8; i++) {
            int u = t + i * 256; int pp = u >> 3, s8 = u & 7;
            *(uint4*)&XT[pp][s8 * 8] =
                *(const uint4*)&xrow[(long)pp * LL + l0 + ((s8 ^ (pp & 7)) << 3)];
        }
        __syncthreads();
        __builtin_amdgcn_s_setprio(1);
#pragma unroll
        for (int ks = 0; ks < 2; ks++) {
            int col = ks * 32 + (lane >> 4) * 8;
            s8 af[4], bx[4];
#pragma unroll
            for (int mi = 0; mi < 4; mi++) {
                int n = mi * 16 + (lane & 15);
                af[mi] = *(const s8*)&BT[n][col ^ ((n & 7) << 3)];
            }
#pragma unroll
            for (int ni = 0; ni < 4; ni++) {
                int p = w * 64 + ni * 16 + (lane & 15);
                bx[ni] = *(const s8*)&XT[p][col ^ ((p & 7) << 3)];
            }
#pragma unroll
            for (int mi = 0; mi < 4; mi++)
#pragma unroll
                for (int ni = 0; ni < 4; ni++)
                    acc[mi][ni] = mfma16(af[mi], bx[ni], acc[mi][ni]);
        }
        __builtin_amdgcn_s_setprio(0);
        __syncthreads();
    }
    bf16* so = st + (long)z * (HD * DS);
#pragma unroll
    for (int mi = 0; mi < 4; mi++)
#pragma unroll
        for (int ni = 0; ni < 4; ni++) {
            int p = w * 64 + ni * 16 + (lane & 15);
            int n0 = mi * 16 + (lane >> 4) * 4;
            bf16 vv[4];
#pragma unroll
            for (int r = 0; r < 4; r++) vv[r] = __float2bfloat16(acc[mi][ni][r]);
            *(uint2*)&so[p * 64 + n0] = *(uint2*)vv;
        }
}

// ---------------- serial chunk scan (in place, bf16, f32 accum in regs) ----------------
__global__ void scan_kernel(bf16* __restrict__ st, const float* __restrict__ csum) {
    long idx = (long)blockIdx.x * 256 + threadIdx.x;
    int pn = (int)(idx & 16383);
    int h = (int)((idx >> 14) & 7);
    int b = (int)(idx >> 17);
    float S = 0.f;
    for (int c = 0; c < NC; c++) {
        long si = (((long)(b * NC + c) * NH + h) * (HD * DS)) + pn;
        float chunk = __bfloat162float(st[si]);
        st[si] = __float2bfloat16(S);
        S = S * __expf(csum[(b * NH + h) * NC + c]) + chunk;
    }
}

// ---------------- fused SSD y via MFMA (v2: [64]-wide tiles, uniform XOR) ----------------
// Convention: LDS[row][phys_blk] holds logical block (phys_blk ^ (row&7)).
__global__ __launch_bounds__(256) void ssd_y_mfma(
        const bf16* __restrict__ bmat, const bf16* __restrict__ cmat,
        const bf16* __restrict__ xdtT, const bf16* __restrict__ st,
        const float* __restrict__ cumA, bf16* __restrict__ y, int ldy) {
    __shared__ __align__(16) bf16 cT[64][64];    // c rows l
    __shared__ __align__(16) bf16 bW[64][64];    // phase1: b rows s; phase2: W rows l
    __shared__ __align__(16) bf16 XTt[256][64];  // X^T rows p; later Y scratch [64][256]
    __shared__ float cumL[64], cumS[64];

    const int t = threadIdx.x, lane = t & 63, w = t >> 6;
    const int bid0 = blockIdx.x;
    const int bid = (bid0 & 7) * 256 + (bid0 >> 3);   // XCD swizzle, grid=2048
    const int zt = bid >> 2, lt = bid & 3;
    const int h = zt & 7, c = (zt >> 3) & 15, b = zt >> 7;
    const long blr = (long)b * LL + (long)c * CHK;
    const int bhc = (b * NH + h) * NC + c;
    const int l0 = lt * 64;
    const bf16* xrow = xdtT + ((long)b * DI + h * HD) * LL + c * CHK;

    // stage c-tile (pre-swizzled source) + cumL
#pragma unroll
    for (int i = 0; i < 2; i++) {
        int u = t + i * 256; int row = u >> 3, pb = u & 7;
        *(uint4*)&cT[row][pb * 8] =
            *(const uint4*)&cmat[(blr + l0 + row) * DS + ((pb ^ (row & 7)) << 3)];
    }
    if (t < 64) cumL[t] = cumA[(long)bhc * CHK + l0 + t];

    f4 acc[4][4];
#pragma unroll
    for (int mi = 0; mi < 4; mi++)
#pragma unroll
        for (int ni = 0; ni < 4; ni++) acc[mi][ni] = (f4){0.f, 0.f, 0.f, 0.f};
    __syncthreads();

    for (int stile = 0; stile <= lt; stile++) {
        const int s0 = stile * 64;
#pragma unroll
        for (int i = 0; i < 2; i++) {
            int u = t + i * 256; int row = u >> 3, pb = u & 7;
            *(uint4*)&bW[row][pb * 8] =
                *(const uint4*)&bmat[(blr + s0 + row) * DS + ((pb ^ (row & 7)) << 3)];
        }
        if (t < 64) cumS[t] = cumA[(long)bhc * CHK + s0 + t];
#pragma unroll
        for (int i = 0; i < 8; i++) {
            int u = t + i * 256; int pp = u >> 3, pb = u & 7;
            *(uint4*)&XTt[pp][pb * 8] =
                *(const uint4*)&xrow[(long)pp * LL + s0 + ((pb ^ (pp & 7)) << 3)];
        }
        __syncthreads();

        // W-gemm: wave w -> W rows [w*16, w*16+16) x 64 s, K=64 (n)
        f4 wacc[4];
#pragma unroll
        for (int ni = 0; ni < 4; ni++) wacc[ni] = (f4){0.f, 0.f, 0.f, 0.f};
        __builtin_amdgcn_s_setprio(1);
#pragma unroll
        for (int ks = 0; ks < 2; ks++) {
            int kb = ks * 4 + (lane >> 4);
            int arow = w * 16 + (lane & 15);
            s8 af = *(const s8*)&cT[arow][(kb ^ (arow & 7)) << 3];
#pragma unroll
            for (int ni = 0; ni < 4; ni++) {
                int brow = ni * 16 + (lane & 15);
                s8 bfr = *(const s8*)&bW[brow][(kb ^ (brow & 7)) << 3];
                wacc[ni] = mfma16(af, bfr, wacc[ni]);
            }
        }
        __builtin_amdgcn_s_setprio(0);
        __syncthreads();  // b-tile reads done before W overwrite

        // epilogue: decay+mask -> bf16 W into bW (swizzled scalar writes)
#pragma unroll
        for (int ni = 0; ni < 4; ni++) {
            int s_idx = ni * 16 + (lane & 15);
#pragma unroll
            for (int r = 0; r < 4; r++) {
                int l_loc = w * 16 + (lane >> 4) * 4 + r;
                bool valid = (stile < lt) || (l_loc >= s_idx);
                float val = valid ? wacc[ni][r] * __expf(cumL[l_loc] - cumS[s_idx]) : 0.f;
                bW[l_loc][(((s_idx >> 3) ^ (l_loc & 7)) << 3) + (s_idx & 7)] =
                    __float2bfloat16(val);
            }
        }
        __syncthreads();

        // Y-gemm: wave w -> 64 l x p-range [w*64, w*64+64), K=64 (s)
        __builtin_amdgcn_s_setprio(1);
#pragma unroll
        for (int ks = 0; ks < 2; ks++) {
            int kb = ks * 4 + (lane >> 4);
            s8 aw[4], bx[4];
#pragma unroll
            for (int mi = 0; mi < 4; mi++) {
                int arow = mi * 16 + (lane & 15);
                aw[mi] = *(const s8*)&bW[arow][(kb ^ (arow & 7)) << 3];
            }
#pragma unroll
            for (int ni = 0; ni < 4; ni++) {
                int p = w * 64 + ni * 16 + (lane & 15);
                bx[ni] = *(const s8*)&XTt[p][(kb ^ (p & 7)) << 3];
            }
#pragma unroll
            for (int mi = 0; mi < 4; mi++)
#pragma unroll
                for (int ni = 0; ni < 4; ni++)
                    acc[mi][ni] = mfma16(aw[mi], bx[ni], acc[mi][ni]);
        }
        __builtin_amdgcn_s_setprio(0);
        __syncthreads();
    }

    // ---- inter-chunk state tile: W = c*exp(cumL), X = st^T ----
#pragma unroll
    for (int i = 0; i < 16; i++) {
        int u = t + i * 256; int l = u >> 6, n = u & 63;
        int pc = (((n >> 3) ^ (l & 7)) << 3) + (n & 7);
        bW[l][pc] = __float2bfloat16(__bfloat162float(cT[l][pc]) * __expf(cumL[l]));
    }
    {
        const bf16* sp = st + (long)zt * (HD * DS) + t * DS;
#pragma unroll
        for (int g = 0; g < 8; g++)
            *(uint4*)&XTt[t][g * 8] = *(const uint4*)&sp[(g ^ (t & 7)) << 3];
    }
    __syncthreads();
    __builtin_amdgcn_s_setprio(1);
#pragma unroll
    for (int ks = 0; ks < 2; ks++) {
        int kb = ks * 4 + (lane >> 4);
        s8 aw[4], bx[4];
#pragma unroll
        for (int mi = 0; mi < 4; mi++) {
            int arow = mi * 16 + (lane & 15);
            aw[mi] = *(const s8*)&bW[arow][(kb ^ (arow & 7)) << 3];
        }
#pragma unroll
        for (int ni = 0; ni < 4; ni++) {
            int p = w * 64 + ni * 16 + (lane & 15);
            bx[ni] = *(const s8*)&XTt[p][(kb ^ (p & 7)) << 3];
        }
#pragma unroll
        for (int mi = 0; mi < 4; mi++)
#pragma unroll
            for (int ni = 0; ni < 4; ni++)
                acc[mi][ni] = mfma16(aw[mi], bx[ni], acc[mi][ni]);
    }
    __builtin_amdgcn_s_setprio(0);
    __syncthreads();

    // ---- epilogue: frags -> LDS -> coalesced global ----
    bf16* Yl = (bf16*)XTt;   // [64][256]
#pragma unroll
    for (int mi = 0; mi < 4; mi++)
#pragma unroll
        for (int ni = 0; ni < 4; ni++)
#pragma unroll
            for (int r = 0; r < 4; r++)
                Yl[(mi * 16 + (lane >> 4) * 4 + r) * 256 + w * 64 + ni * 16 + (lane & 15)] =
                    __float2bfloat16(acc[mi][ni][r]);
    __syncthreads();
#pragma unroll
    for (int i = 0; i < 8; i++) {
        int u = t + i * 256; int l = u >> 5, p8 = u & 31;
        *(uint4*)&y[(blr + l0 + l) * (long)ldy + h * HD + p8 * 8] =
            *(uint4*)&Yl[l * 256 + p8 * 8];
    }
}

// ---------------- gate (silu(z)) + RMSNorm, strided over zxbc ----------------
__global__ void gatenorm_kernel(const bf16* __restrict__ zxbc,
                                const float* __restrict__ gamma, bf16* __restrict__ out) {
    int row = blockIdx.x;
    int tid = threadIdx.x;
    int d0 = tid * 8;
    bf16 yv[8], zv[8];
    *(uint4*)yv = *(const uint4*)&zxbc[(long)row * ZXW + DI + d0];  // y (over xbc cols)
    *(uint4*)zv = *(const uint4*)&zxbc[(long)row * ZXW + d0];       // z
    float g[8];
    float ss = 0.f;
#pragma unroll
    for (int i = 0; i < 8; i++) {
        float zf = __bfloat162float(zv[i]);
        float gate = zf / (1.f + __expf(-zf));
        float v = __bfloat162float(yv[i]) * gate;
        g[i] = v;
        ss += v * v;
    }
#pragma unroll
    for (int off = 32; off > 0; off >>= 1) ss += __shfl_down(ss, off);
    __shared__ float red[4];
    if ((tid & 63) == 0) red[tid >> 6] = ss;
    __syncthreads();
    float tot = red[0] + red[1] + red[2] + red[3];
    float scale = rsqrtf(tot / (float)DI + 1e-5f);
    float4 g0 = *(const float4*)&gamma[d0];
    float4 g1 = *(const float4*)&gamma[d0 + 4];
    bf16 o[8];
    o[0] = __float2bfloat16(g[0] * scale * g0.x);
    o[1] = __float2bfloat16(g[1] * scale * g0.y);
    o[2] = __float2bfloat16(g[2] * scale * g0.z);
    o[3] = __float2bfloat16(g[3] * scale * g0.w);
    o[4] = __float2bfloat16(g[4] * scale * g1.x);
    o[5] = __float2bfloat16(g[5] * scale * g1.y);
    o[6] = __float2bfloat16(g[6] * scale * g1.z);
    o[7] = __float2bfloat16(g[7] * scale * g1.w);
    *(uint4*)&out[(long)row * ZXW + DI + d0] = *(uint4*)o;  // ynorm in place
}

extern "C" void kernel_launch(void* const* d_in, const int* in_sizes, int n_in,
                              void* d_out, int out_size, void* d_ws, size_t ws_size,
                              hipStream_t stream) {
    const float* inputs = (const float*)d_in[0];
    const float* Wz = (const float*)d_in[1];
    const float* Wxbc = (const float*)d_in[2];
    const float* Wdt = (const float*)d_in[3];
    const float* conv_kernel = (const float*)d_in[4];
    const float* dt_bias = (const float*)d_in[5];
    const float* a_log = (const float*)d_in[6];
    const float* gamma = (const float*)d_in[7];
    const float* Wout = (const float*)d_in[8];
    float* out = (float*)d_out;

    // ---- workspace layout (~223 MiB) ----
    char* p = (char*)d_ws;
    float* dtb = (float*)p;      p += (long)MROWS * NH * 4;
    float* cumA = (float*)p;     p += (long)MROWS * NH * 4;
    float* csum = (float*)p;     p += 512 * 4;
    bf16* WzT = (bf16*)p;        p += (long)DI * DM * 2;      // [WzT;WxbcT] adjacent
    bf16* WxbcT = (bf16*)p;      p += (long)CONVD * DM * 2;   //  = [4224][512]
    bf16* WoutT = (bf16*)p;      p += (long)DM * DI * 2;
    bf16* bmat = (bf16*)p;       p += (long)MROWS * DS * 2;
    bf16* cmat = (bf16*)p;       p += (long)MROWS * DS * 2;
    bf16* inA = (bf16*)p;        p += (long)MROWS * DM * 2;   // -> st (bf16) after GEMM
    bf16* zxbc = (bf16*)p;       p += (long)MROWS * ZXW * 2;  // 138.4 MB: z|xbc -> z|y -> z|ynorm
    bf16* xdtT = (bf16*)p;       p += (long)DI * BB * LL * 2; // 67 MB
    bf16* st = inA;

    // 1. casts / weight transposes
    cast_bf16_kernel<<<MROWS * DM / 8 / 256, 256, 0, stream>>>(inputs, inA);
    tcast_kernel<<<dim3(DI / 64, DM / 64), 256, 0, stream>>>(Wz, WzT, DM, DI);
    tcast_kernel<<<dim3(CONVD / 64, DM / 64), 256, 0, stream>>>(Wxbc, WxbcT, DM, CONVD);
    tcast_kernel<<<dim3(DM / 64, DI / 64), 256, 0, stream>>>(Wout, WoutT, DI, DM);
    // 2. zxbc = inA @ [Wz | Wxbc]   (N = 4224)
    mfma_gemm<bf16><<<dim3(ZXW / 128, MROWS / 128), 256, 0, stream>>>(
        inA, WzT, zxbc, ZXW, DM, DM, ZXW);
    // 3. dt
    dt_kernel<<<MROWS * NH / 256, 256, 0, stream>>>(inputs, Wdt, dt_bias, dtb);
    // 4. conv x-part -> xdtT (transposed);  b/c part -> bmat/cmat
    conv_x<<<BB * 64 * 32, 256, 0, stream>>>(zxbc, conv_kernel, dtb, xdtT);
    conv_bc<<<MROWS * 128 / 8 / 256, 256, 0, stream>>>(zxbc, conv_kernel, bmat, cmat);
    // 5. cumsum
    cumsum_kernel<<<2, 256, 0, stream>>>(dtb, a_log, cumA, csum);
    // 6. per-chunk states (MFMA) -> st (bf16, over dead inA)
    states_mfma<<<BB * NC * NH, 256, 0, stream>>>(bmat, xdtT, cumA, csum, st);
    // 7. chunk scan (in place)
    scan_kernel<<<BB * NH * HD * DS / 256, 256, 0, stream>>>(st, csum);
    // 8. fused SSD y (MFMA) -> y cols of zxbc (xbc dead after conv)
    ssd_y_mfma<<<BB * NC * NH * 4, 256, 0, stream>>>(
        bmat, cmat, xdtT, st, cumA, zxbc + DI, ZXW);
    // 9. gate + rmsnorm (ynorm in place over y)
    gatenorm_kernel<<<MROWS, 256, 0, stream>>>(zxbc, gamma, zxbc);
    // 10. out = ynorm @ Wout   (A strided inside zxbc)
    mfma_gemm<float><<<dim3(DM / 128, MROWS / 128), 256, 0, stream>>>(
        zxbc + DI, WoutT, out, DM, DI, ZXW, DM);
}

// Round 7
// 372.748 us; speedup vs baseline: 15.4240x; 1.0400x over previous
//
#include <hip/hip_runtime.h>
#include <hip/hip_bf16.h>

// Mamba2 block forward. B=4 L=4096 D_MODEL=512 D_INNER=2048 H=8 P=256 N=64
// CHUNK=256 C=16 CONV_DIM=2176.
// Round 7: mfma_gemm gets (a) XCD-banded bijective block swizzle (FETCH was
// 200MB vs ~21MB ideal - L2 thrash across 8 XCDs), (b) LDS-staged coalesced
// C writeback for bf16 outputs. Everything else unchanged from round 6.

#define BB 4
#define LL 4096
#define DM 512
#define DI 2048
#define NH 8
#define HD 256
#define DS 64
#define DCONV 4
#define CHK 256
#define NC 16
#define CONVD 2176
#define MROWS (BB*LL)   // 16384
#define ZXW (DI + CONVD) // 4224

typedef __hip_bfloat16 bf16;
typedef short s8 __attribute__((ext_vector_type(8)));   // 8 bf16 (4 VGPRs)
typedef float f4 __attribute__((ext_vector_type(4)));   // MFMA acc

__device__ __forceinline__ f4 mfma16(s8 a, s8 b, f4 c) {
    return __builtin_amdgcn_mfma_f32_16x16x32_bf16(a, b, c, 0, 0, 0);
}

__device__ __forceinline__ void gload16(const bf16* g, bf16* l) {
    __builtin_amdgcn_global_load_lds(
        (const __attribute__((address_space(1))) void*)g,
        (__attribute__((address_space(3))) void*)l, 16, 0, 0);
}

__device__ __forceinline__ float ldf(const float* p) { return *p; }
__device__ __forceinline__ float ldf(const bf16* p) { return __bfloat162float(*p); }
__device__ __forceinline__ void stf(float* p, float v) { *p = v; }
__device__ __forceinline__ void stf(bf16* p, float v) { *p = __float2bfloat16(v); }

// ---------------- f32 -> bf16 cast (8/thread) ----------------
__global__ void cast_bf16_kernel(const float* __restrict__ in, bf16* __restrict__ out) {
    long i8 = ((long)blockIdx.x * 256 + threadIdx.x) * 8;
    float4 a = *(const float4*)&in[i8];
    float4 b = *(const float4*)&in[i8 + 4];
    bf16 v[8];
    v[0] = __float2bfloat16(a.x); v[1] = __float2bfloat16(a.y);
    v[2] = __float2bfloat16(a.z); v[3] = __float2bfloat16(a.w);
    v[4] = __float2bfloat16(b.x); v[5] = __float2bfloat16(b.y);
    v[6] = __float2bfloat16(b.z); v[7] = __float2bfloat16(b.w);
    *(uint4*)&out[i8] = *(uint4*)v;
}

// ---------------- f32 [K][N] -> bf16 [N][K] transpose-cast (weights) ----------------
__global__ void tcast_kernel(const float* __restrict__ in, bf16* __restrict__ out,
                             int K, int N) {
    __shared__ float tile[64][65];
    int t = threadIdx.x;
    int n0 = blockIdx.x * 64, k0 = blockIdx.y * 64;
#pragma unroll
    for (int i = 0; i < 16; i++) {
        int u = t + i * 256; int kr = u >> 6, nc = u & 63;
        tile[kr][nc] = in[(long)(k0 + kr) * N + n0 + nc];
    }
    __syncthreads();
#pragma unroll
    for (int i = 0; i < 16; i++) {
        int u = t + i * 256; int nr = u >> 6, kc = u & 63;
        out[(long)(n0 + nr) * K + k0 + kc] = __float2bfloat16(tile[kc][nr]);
    }
}

// ---------------- bf16 MFMA GEMM: C[M][N] = A[M][K] @ BT[N][K]^T ----------------
// 128x128 tile, BK=64, 4 waves. 1D grid = 128 * nNt blocks (M-tiles MUST be 128).
// XCD-banded swizzle: xcd=bid&7 owns M-tiles [xcd*16, xcd*16+16); within a band
// the M-tile varies fastest so the current B-tile stays L2-resident.
template <typename TC>
__global__ __launch_bounds__(256) void mfma_gemm(const bf16* __restrict__ A,
                                                 const bf16* __restrict__ BT,
                                                 TC* __restrict__ C, int N, int K,
                                                 int lda, int ldc) {
    __shared__ __align__(16) char smem[34816];  // staging 32KB | bf16 C-epilogue 34KB
    bf16 (*At)[64] = (bf16(*)[64])smem;
    bf16 (*Bt)[64] = (bf16(*)[64])(smem + 16384);
    const int t = threadIdx.x, lane = t & 63, w = t >> 6;
    const int wr = w >> 1, wc = w & 1;
    const int bid = blockIdx.x;
    const int idx = bid >> 3;
    const int mt = (bid & 7) * 16 + (idx & 15);   // nMt = 128 fixed
    const int nt = idx >> 4;
    const long m0 = (long)mt * 128;
    const int n0 = nt * 128;
    const int lrow = lane >> 3, lblk = lane & 7;
    f4 acc[4][4];
#pragma unroll
    for (int mi = 0; mi < 4; mi++)
#pragma unroll
        for (int ni = 0; ni < 4; ni++) acc[mi][ni] = (f4){0.f, 0.f, 0.f, 0.f};

    for (int k0 = 0; k0 < K; k0 += 64) {
#pragma unroll
        for (int i = 0; i < 4; i++) {
            int rbase = w * 32 + i * 8;
            int row = rbase + lrow;
            int kb = (lblk ^ (row & 7)) << 3;   // source k-block, pre-swizzled
            gload16(&A[(m0 + row) * (long)lda + k0 + kb], &At[rbase][0]);
            gload16(&BT[((long)n0 + row) * K + k0 + kb], &Bt[rbase][0]);
        }
        __syncthreads();
        __builtin_amdgcn_s_setprio(1);
#pragma unroll
        for (int ks = 0; ks < 2; ks++) {
            int k8 = ks * 4 + (lane >> 4);
            s8 af[4], bfr[4];
#pragma unroll
            for (int mi = 0; mi < 4; mi++) {
                int row = wr * 64 + mi * 16 + (lane & 15);
                af[mi] = *(const s8*)&At[row][(k8 ^ (row & 7)) << 3];
            }
#pragma unroll
            for (int ni = 0; ni < 4; ni++) {
                int row = wc * 64 + ni * 16 + (lane & 15);
                bfr[ni] = *(const s8*)&Bt[row][(k8 ^ (row & 7)) << 3];
            }
#pragma unroll
            for (int mi = 0; mi < 4; mi++)
#pragma unroll
                for (int ni = 0; ni < 4; ni++)
                    acc[mi][ni] = mfma16(af[mi], bfr[ni], acc[mi][ni]);
        }
        __builtin_amdgcn_s_setprio(0);
        __syncthreads();
    }
    if constexpr (sizeof(TC) == 2) {
        // LDS-staged coalesced writeback (rows 272B, 16B-aligned)
        bf16 (*Ct)[136] = (bf16(*)[136])smem;
#pragma unroll
        for (int mi = 0; mi < 4; mi++)
#pragma unroll
            for (int ni = 0; ni < 4; ni++)
#pragma unroll
                for (int r = 0; r < 4; r++)
                    Ct[wr * 64 + mi * 16 + (lane >> 4) * 4 + r]
                      [wc * 64 + ni * 16 + (lane & 15)] =
                        __float2bfloat16(acc[mi][ni][r]);
        __syncthreads();
#pragma unroll
        for (int i = 0; i < 8; i++) {
            int u = t + i * 256; int row = u >> 4, j = u & 15;
            *(uint4*)&C[(m0 + row) * (long)ldc + n0 + j * 8] = *(uint4*)&Ct[row][j * 8];
        }
    } else {
#pragma unroll
        for (int mi = 0; mi < 4; mi++)
#pragma unroll
            for (int ni = 0; ni < 4; ni++)
#pragma unroll
                for (int r = 0; r < 4; r++)
                    stf(&C[(m0 + wr * 64 + mi * 16 + (lane >> 4) * 4 + r) * (long)ldc +
                           n0 + wc * 64 + ni * 16 + (lane & 15)], acc[mi][ni][r]);
    }
}

// ---------------- dt = softplus(inputs @ Wdt + bias) ----------------
__global__ void dt_kernel(const float* __restrict__ inp, const float* __restrict__ Wdt,
                          const float* __restrict__ dt_bias, float* __restrict__ dtb) {
    __shared__ float wlds[DM * NH];  // 16 KB
    int t = threadIdx.x;
#pragma unroll
    for (int i = 0; i < 16; i++) wlds[t + i * 256] = Wdt[t + i * 256];
    __syncthreads();
    int idx = blockIdx.x * 256 + t;
    int h = idx & 7;
    long row = idx >> 3;
    const float* ir = inp + row * DM;
    float acc = 0.f;
    for (int k = 0; k < DM; k += 4) {
        float4 a = *(const float4*)&ir[k];
        acc += a.x * wlds[k * 8 + h] + a.y * wlds[(k + 1) * 8 + h]
             + a.z * wlds[(k + 2) * 8 + h] + a.w * wlds[(k + 3) * 8 + h];
    }
    acc += dt_bias[h];
    float sp = acc > 20.f ? acc : log1pf(expf(acc));
    dtb[idx] = sp;
}

// ---------------- conv_x: conv(4)+silu+*dt over x channels, writes xdtT ----------------
__global__ __launch_bounds__(256) void conv_x(const bf16* __restrict__ zxbc,
                                              const float* __restrict__ ck,
                                              const float* __restrict__ dtb,
                                              bf16* __restrict__ xdtT) {
    __shared__ __align__(16) bf16 in_lds[67][72];
    __shared__ __align__(16) bf16 out_lds[64][64];
    __shared__ float dts[64];
    const int bid = blockIdx.x;
    const int ct = bid & 31, lt = (bid >> 5) & 63, b = bid >> 11;
    const int t = threadIdx.x;
    const int l0 = lt * 64;
    const long brow = (long)b * LL;
    const int h = ct >> 2;

#pragma unroll
    for (int i = 0; i < 3; i++) {
        int u = t + i * 256;
        if (u < 536) {
            int r = u >> 3, c8 = (u & 7) * 8;
            int gl = l0 - 3 + r;
            uint4 v = (gl >= 0)
                ? *(const uint4*)&zxbc[(brow + gl) * ZXW + DI + ct * 64 + c8]
                : (uint4){0, 0, 0, 0};
            *(uint4*)&in_lds[r][c8] = v;
        }
    }
    if (t < 64) dts[t] = dtb[(brow + l0 + t) * NH + h];
    __syncthreads();

    const int ch = t & 63, w = t >> 6;
    const int gch = ct * 64 + ch;
    float k0 = ck[0 * CONVD + gch], k1 = ck[1 * CONVD + gch];
    float k2 = ck[2 * CONVD + gch], k3 = ck[3 * CONVD + gch];
    float w0 = __bfloat162float(in_lds[w * 16 + 0][ch]);
    float w1 = __bfloat162float(in_lds[w * 16 + 1][ch]);
    float w2 = __bfloat162float(in_lds[w * 16 + 2][ch]);
    bf16 o[16];
#pragma unroll
    for (int i = 0; i < 16; i++) {
        float w3 = __bfloat162float(in_lds[w * 16 + i + 3][ch]);
        float v = w0 * k0 + w1 * k1 + w2 * k2 + w3 * k3;
        float s = v / (1.f + __expf(-v));
        o[i] = __float2bfloat16(s * dts[w * 16 + i]);
        w0 = w1; w1 = w2; w2 = w3;
    }
#pragma unroll
    for (int j = 0; j < 2; j++) {
        int blk = w * 2 + j;
        *(uint4*)&out_lds[ch][((blk ^ (ch & 7)) << 3)] = *(uint4*)&o[j * 8];
    }
    __syncthreads();
#pragma unroll
    for (int i = 0; i < 2; i++) {
        int u = t + i * 256;
        int chr = u >> 3, l8 = u & 7;
        uint4 v = *(const uint4*)&out_lds[chr][((l8 ^ (chr & 7)) << 3)];
        *(uint4*)&xdtT[((long)b * DI + ct * 64 + chr) * LL + l0 + l8 * 8] = v;
    }
}

// ---------------- conv_bc: conv+silu for b/c channels ----------------
__global__ void conv_bc(const bf16* __restrict__ zxbc, const float* __restrict__ ck,
                        bf16* __restrict__ bm, bf16* __restrict__ cm) {
    long idx = (long)blockIdx.x * 256 + threadIdx.x;
    if (idx >= (long)MROWS * 128 / 8) return;
    long e0 = idx * 8;
    int ch = (int)(e0 & 127);
    long bl = e0 >> 7;
    int l = (int)(bl & (LL - 1));
    float acc[8] = {};
#pragma unroll
    for (int k = 0; k < DCONV; k++) {
        int ls = l - 3 + k;
        if (ls >= 0) {
            bf16 v[8];
            *(uint4*)v = *(const uint4*)&zxbc[(bl - l + ls) * ZXW + 2 * DI + ch];
            float4 c0 = *(const float4*)&ck[k * CONVD + DI + ch];
            float4 c1 = *(const float4*)&ck[k * CONVD + DI + ch + 4];
            acc[0] += __bfloat162float(v[0]) * c0.x;
            acc[1] += __bfloat162float(v[1]) * c0.y;
            acc[2] += __bfloat162float(v[2]) * c0.z;
            acc[3] += __bfloat162float(v[3]) * c0.w;
            acc[4] += __bfloat162float(v[4]) * c1.x;
            acc[5] += __bfloat162float(v[5]) * c1.y;
            acc[6] += __bfloat162float(v[6]) * c1.z;
            acc[7] += __bfloat162float(v[7]) * c1.w;
        }
    }
    bf16 o[8];
#pragma unroll
    for (int j = 0; j < 8; j++) {
        float s = acc[j] / (1.f + __expf(-acc[j]));
        o[j] = __float2bfloat16(s);
    }
    if (ch < DS) *(uint4*)&bm[bl * DS + ch] = *(uint4*)o;
    else         *(uint4*)&cm[bl * DS + (ch - DS)] = *(uint4*)o;
}

// ---------------- per-(b,h,c) cumsum of a*dt ----------------
__global__ void cumsum_kernel(const float* __restrict__ dtb, const float* __restrict__ a_log,
                              float* __restrict__ cumA, float* __restrict__ csum) {
    int t = blockIdx.x * 256 + threadIdx.x;  // t = b*128 + h*16 + c
    if (t >= BB * NH * NC) return;
    int c = t & 15, h = (t >> 4) & 7, b = t >> 7;
    float a = -expf(a_log[h]);
    long base_l = (long)b * LL + (long)c * CHK;
    float s = 0.f;
    long obase = (long)t * CHK;
    for (int i = 0; i < CHK; i++) {
        s += a * dtb[(base_l + i) * NH + h];
        cumA[obase + i] = s;
    }
    csum[t] = s;
}

// ---------------- states via MFMA: st[p][n] = sum_l x[l,p]*b[l,n]*dec[l] ----------------
__global__ __launch_bounds__(256) void states_mfma(
        const bf16* __restrict__ bmat, const bf16* __restrict__ xdtT,
        const float* __restrict__ cumA, const float* __restrict__ csum,
        bf16* __restrict__ st) {
    __shared__ __align__(16) bf16 XT[256][72];
    __shared__ __align__(16) bf16 BT[64][72];
    const int z = blockIdx.x;  // b*128 + c*8 + h
    const int h = z & 7, c = (z >> 3) & 15, b = z >> 7;
    const long blr = (long)b * LL + (long)c * CHK;
    const int bhc = (b * NH + h) * NC + c;
    const float A = csum[bhc];
    const int t = threadIdx.x, lane = t & 63, w = t >> 6;
    const bf16* xrow = xdtT + ((long)b * DI + h * HD) * LL + c * CHK;
    f4 acc[4][4];
#pragma unroll
    for (int mi = 0; mi < 4; mi++)
#pragma unroll
        for (int ni = 0; ni < 4; ni++) acc[mi][ni] = (f4){0.f, 0.f, 0.f, 0.f};

    for (int lt = 0; lt < 4; lt++) {
        const int l0 = lt * 64;
#pragma unroll
        for (int i = 0; i < 2; i++) {
            int u = t + i * 256; int l = u >> 3, n8 = (u & 7) * 8;
            bf16 v[8];
            *(uint4*)v = *(const uint4*)&bmat[(blr + l0 + l) * DS + n8];
            float d = __expf(A - cumA[(long)bhc * CHK + l0 + l]);
#pragma unroll
            for (int j = 0; j < 8; j++) {
                int n = n8 + j;
                BT[n][l ^ ((n & 7) << 3)] = __float2bfloat16(__bfloat162float(v[j]) * d);
            }
        }
#pragma unroll
        for (int i = 0; i < 8; i++) {
            int u = t + i * 256; int pp = u >> 3, s8 = u & 7;
            *(uint4*)&XT[pp][s8 * 8] =
                *(const uint4*)&xrow[(long)pp * LL + l0 + ((s8 ^ (pp & 7)) << 3)];
        }
        __syncthreads();
        __builtin_amdgcn_s_setprio(1);
#pragma unroll
        for (int ks = 0; ks < 2; ks++) {
            int col = ks * 32 + (lane >> 4) * 8;
            s8 af[4], bx[4];
#pragma unroll
            for (int mi = 0; mi < 4; mi++) {
                int n = mi * 16 + (lane & 15);
                af[mi] = *(const s8*)&BT[n][col ^ ((n & 7) << 3)];
            }
#pragma unroll
            for (int ni = 0; ni < 4; ni++) {
                int p = w * 64 + ni * 16 + (lane & 15);
                bx[ni] = *(const s8*)&XT[p][col ^ ((p & 7) << 3)];
            }
#pragma unroll
            for (int mi = 0; mi < 4; mi++)
#pragma unroll
                for (int ni = 0; ni < 4; ni++)
                    acc[mi][ni] = mfma16(af[mi], bx[ni], acc[mi][ni]);
        }
        __builtin_amdgcn_s_setprio(0);
        __syncthreads();
    }
    bf16* so = st + (long)z * (HD * DS);
#pragma unroll
    for (int mi = 0; mi < 4; mi++)
#pragma unroll
        for (int ni = 0; ni < 4; ni++) {
            int p = w * 64 + ni * 16 + (lane & 15);
            int n0 = mi * 16 + (lane >> 4) * 4;
            bf16 vv[4];
#pragma unroll
            for (int r = 0; r < 4; r++) vv[r] = __float2bfloat16(acc[mi][ni][r]);
            *(uint2*)&so[p * 64 + n0] = *(uint2*)vv;
        }
}

// ---------------- serial chunk scan (in place, bf16, f32 accum in regs) ----------------
__global__ void scan_kernel(bf16* __restrict__ st, const float* __restrict__ csum) {
    long idx = (long)blockIdx.x * 256 + threadIdx.x;
    int pn = (int)(idx & 16383);
    int h = (int)((idx >> 14) & 7);
    int b = (int)(idx >> 17);
    float S = 0.f;
    for (int c = 0; c < NC; c++) {
        long si = (((long)(b * NC + c) * NH + h) * (HD * DS)) + pn;
        float chunk = __bfloat162float(st[si]);
        st[si] = __float2bfloat16(S);
        S = S * __expf(csum[(b * NH + h) * NC + c]) + chunk;
    }
}

// ---------------- fused SSD y via MFMA (uniform XOR-swizzle convention) ----------------
__global__ __launch_bounds__(256) void ssd_y_mfma(
        const bf16* __restrict__ bmat, const bf16* __restrict__ cmat,
        const bf16* __restrict__ xdtT, const bf16* __restrict__ st,
        const float* __restrict__ cumA, bf16* __restrict__ y, int ldy) {
    __shared__ __align__(16) bf16 cT[64][64];
    __shared__ __align__(16) bf16 bW[64][64];
    __shared__ __align__(16) bf16 XTt[256][64];
    __shared__ float cumL[64], cumS[64];

    const int t = threadIdx.x, lane = t & 63, w = t >> 6;
    const int bid0 = blockIdx.x;
    const int bid = (bid0 & 7) * 256 + (bid0 >> 3);   // XCD swizzle, grid=2048
    const int zt = bid >> 2, lt = bid & 3;
    const int h = zt & 7, c = (zt >> 3) & 15, b = zt >> 7;
    const long blr = (long)b * LL + (long)c * CHK;
    const int bhc = (b * NH + h) * NC + c;
    const int l0 = lt * 64;
    const bf16* xrow = xdtT + ((long)b * DI + h * HD) * LL + c * CHK;

#pragma unroll
    for (int i = 0; i < 2; i++) {
        int u = t + i * 256; int row = u >> 3, pb = u & 7;
        *(uint4*)&cT[row][pb * 8] =
            *(const uint4*)&cmat[(blr + l0 + row) * DS + ((pb ^ (row & 7)) << 3)];
    }
    if (t < 64) cumL[t] = cumA[(long)bhc * CHK + l0 + t];

    f4 acc[4][4];
#pragma unroll
    for (int mi = 0; mi < 4; mi++)
#pragma unroll
        for (int ni = 0; ni < 4; ni++) acc[mi][ni] = (f4){0.f, 0.f, 0.f, 0.f};
    __syncthreads();

    for (int stile = 0; stile <= lt; stile++) {
        const int s0 = stile * 64;
#pragma unroll
        for (int i = 0; i < 2; i++) {
            int u = t + i * 256; int row = u >> 3, pb = u & 7;
            *(uint4*)&bW[row][pb * 8] =
                *(const uint4*)&bmat[(blr + s0 + row) * DS + ((pb ^ (row & 7)) << 3)];
        }
        if (t < 64) cumS[t] = cumA[(long)bhc * CHK + s0 + t];
#pragma unroll
        for (int i = 0; i < 8; i++) {
            int u = t + i * 256; int pp = u >> 3, pb = u & 7;
            *(uint4*)&XTt[pp][pb * 8] =
                *(const uint4*)&xrow[(long)pp * LL + s0 + ((pb ^ (pp & 7)) << 3)];
        }
        __syncthreads();

        f4 wacc[4];
#pragma unroll
        for (int ni = 0; ni < 4; ni++) wacc[ni] = (f4){0.f, 0.f, 0.f, 0.f};
        __builtin_amdgcn_s_setprio(1);
#pragma unroll
        for (int ks = 0; ks < 2; ks++) {
            int kb = ks * 4 + (lane >> 4);
            int arow = w * 16 + (lane & 15);
            s8 af = *(const s8*)&cT[arow][(kb ^ (arow & 7)) << 3];
#pragma unroll
            for (int ni = 0; ni < 4; ni++) {
                int brow = ni * 16 + (lane & 15);
                s8 bfr = *(const s8*)&bW[brow][(kb ^ (brow & 7)) << 3];
                wacc[ni] = mfma16(af, bfr, wacc[ni]);
            }
        }
        __builtin_amdgcn_s_setprio(0);
        __syncthreads();

#pragma unroll
        for (int ni = 0; ni < 4; ni++) {
            int s_idx = ni * 16 + (lane & 15);
#pragma unroll
            for (int r = 0; r < 4; r++) {
                int l_loc = w * 16 + (lane >> 4) * 4 + r;
                bool valid = (stile < lt) || (l_loc >= s_idx);
                float val = valid ? wacc[ni][r] * __expf(cumL[l_loc] - cumS[s_idx]) : 0.f;
                bW[l_loc][(((s_idx >> 3) ^ (l_loc & 7)) << 3) + (s_idx & 7)] =
                    __float2bfloat16(val);
            }
        }
        __syncthreads();

        __builtin_amdgcn_s_setprio(1);
#pragma unroll
        for (int ks = 0; ks < 2; ks++) {
            int kb = ks * 4 + (lane >> 4);
            s8 aw[4], bx[4];
#pragma unroll
            for (int mi = 0; mi < 4; mi++) {
                int arow = mi * 16 + (lane & 15);
                aw[mi] = *(const s8*)&bW[arow][(kb ^ (arow & 7)) << 3];
            }
#pragma unroll
            for (int ni = 0; ni < 4; ni++) {
                int p = w * 64 + ni * 16 + (lane & 15);
                bx[ni] = *(const s8*)&XTt[p][(kb ^ (p & 7)) << 3];
            }
#pragma unroll
            for (int mi = 0; mi < 4; mi++)
#pragma unroll
                for (int ni = 0; ni < 4; ni++)
                    acc[mi][ni] = mfma16(aw[mi], bx[ni], acc[mi][ni]);
        }
        __builtin_amdgcn_s_setprio(0);
        __syncthreads();
    }

#pragma unroll
    for (int i = 0; i < 16; i++) {
        int u = t + i * 256; int l = u >> 6, n = u & 63;
        int pc = (((n >> 3) ^ (l & 7)) << 3) + (n & 7);
        bW[l][pc] = __float2bfloat16(__bfloat162float(cT[l][pc]) * __expf(cumL[l]));
    }
    {
        const bf16* sp = st + (long)zt * (HD * DS) + t * DS;
#pragma unroll
        for (int g = 0; g < 8; g++)
            *(uint4*)&XTt[t][g * 8] = *(const uint4*)&sp[(g ^ (t & 7)) << 3];
    }
    __syncthreads();
    __builtin_amdgcn_s_setprio(1);
#pragma unroll
    for (int ks = 0; ks < 2; ks++) {
        int kb = ks * 4 + (lane >> 4);
        s8 aw[4], bx[4];
#pragma unroll
        for (int mi = 0; mi < 4; mi++) {
            int arow = mi * 16 + (lane & 15);
            aw[mi] = *(const s8*)&bW[arow][(kb ^ (arow & 7)) << 3];
        }
#pragma unroll
        for (int ni = 0; ni < 4; ni++) {
            int p = w * 64 + ni * 16 + (lane & 15);
            bx[ni] = *(const s8*)&XTt[p][(kb ^ (p & 7)) << 3];
        }
#pragma unroll
        for (int mi = 0; mi < 4; mi++)
#pragma unroll
            for (int ni = 0; ni < 4; ni++)
                acc[mi][ni] = mfma16(aw[mi], bx[ni], acc[mi][ni]);
    }
    __builtin_amdgcn_s_setprio(0);
    __syncthreads();

    bf16* Yl = (bf16*)XTt;   // [64][256]
#pragma unroll
    for (int mi = 0; mi < 4; mi++)
#pragma unroll
        for (int ni = 0; ni < 4; ni++)
#pragma unroll
            for (int r = 0; r < 4; r++)
                Yl[(mi * 16 + (lane >> 4) * 4 + r) * 256 + w * 64 + ni * 16 + (lane & 15)] =
                    __float2bfloat16(acc[mi][ni][r]);
    __syncthreads();
#pragma unroll
    for (int i = 0; i < 8; i++) {
        int u = t + i * 256; int l = u >> 5, p8 = u & 31;
        *(uint4*)&y[(blr + l0 + l) * (long)ldy + h * HD + p8 * 8] =
            *(uint4*)&Yl[l * 256 + p8 * 8];
    }
}

// ---------------- gate (silu(z)) + RMSNorm, strided over zxbc ----------------
__global__ void gatenorm_kernel(const bf16* __restrict__ zxbc,
                                const float* __restrict__ gamma, bf16* __restrict__ out) {
    int row = blockIdx.x;
    int tid = threadIdx.x;
    int d0 = tid * 8;
    bf16 yv[8], zv[8];
    *(uint4*)yv = *(const uint4*)&zxbc[(long)row * ZXW + DI + d0];  // y (over xbc cols)
    *(uint4*)zv = *(const uint4*)&zxbc[(long)row * ZXW + d0];       // z
    float g[8];
    float ss = 0.f;
#pragma unroll
    for (int i = 0; i < 8; i++) {
        float zf = __bfloat162float(zv[i]);
        float gate = zf / (1.f + __expf(-zf));
        float v = __bfloat162float(yv[i]) * gate;
        g[i] = v;
        ss += v * v;
    }
#pragma unroll
    for (int off = 32; off > 0; off >>= 1) ss += __shfl_down(ss, off);
    __shared__ float red[4];
    if ((tid & 63) == 0) red[tid >> 6] = ss;
    __syncthreads();
    float tot = red[0] + red[1] + red[2] + red[3];
    float scale = rsqrtf(tot / (float)DI + 1e-5f);
    float4 g0 = *(const float4*)&gamma[d0];
    float4 g1 = *(const float4*)&gamma[d0 + 4];
    bf16 o[8];
    o[0] = __float2bfloat16(g[0] * scale * g0.x);
    o[1] = __float2bfloat16(g[1] * scale * g0.y);
    o[2] = __float2bfloat16(g[2] * scale * g0.z);
    o[3] = __float2bfloat16(g[3] * scale * g0.w);
    o[4] = __float2bfloat16(g[4] * scale * g1.x);
    o[5] = __float2bfloat16(g[5] * scale * g1.y);
    o[6] = __float2bfloat16(g[6] * scale * g1.z);
    o[7] = __float2bfloat16(g[7] * scale * g1.w);
    *(uint4*)&out[(long)row * ZXW + DI + d0] = *(uint4*)o;  // ynorm in place
}

extern "C" void kernel_launch(void* const* d_in, const int* in_sizes, int n_in,
                              void* d_out, int out_size, void* d_ws, size_t ws_size,
                              hipStream_t stream) {
    const float* inputs = (const float*)d_in[0];
    const float* Wz = (const float*)d_in[1];
    const float* Wxbc = (const float*)d_in[2];
    const float* Wdt = (const float*)d_in[3];
    const float* conv_kernel = (const float*)d_in[4];
    const float* dt_bias = (const float*)d_in[5];
    const float* a_log = (const float*)d_in[6];
    const float* gamma = (const float*)d_in[7];
    const float* Wout = (const float*)d_in[8];
    float* out = (float*)d_out;

    // ---- workspace layout (~223 MiB) ----
    char* p = (char*)d_ws;
    float* dtb = (float*)p;      p += (long)MROWS * NH * 4;
    float* cumA = (float*)p;     p += (long)MROWS * NH * 4;
    float* csum = (float*)p;     p += 512 * 4;
    bf16* WzT = (bf16*)p;        p += (long)DI * DM * 2;      // [WzT;WxbcT] adjacent
    bf16* WxbcT = (bf16*)p;      p += (long)CONVD * DM * 2;   //  = [4224][512]
    bf16* WoutT = (bf16*)p;      p += (long)DM * DI * 2;
    bf16* bmat = (bf16*)p;       p += (long)MROWS * DS * 2;
    bf16* cmat = (bf16*)p;       p += (long)MROWS * DS * 2;
    bf16* inA = (bf16*)p;        p += (long)MROWS * DM * 2;   // -> st (bf16) after GEMM
    bf16* zxbc = (bf16*)p;       p += (long)MROWS * ZXW * 2;  // z|xbc -> z|y -> z|ynorm
    bf16* xdtT = (bf16*)p;       p += (long)DI * BB * LL * 2; // 67 MB
    bf16* st = inA;

    // 1. casts / weight transposes
    cast_bf16_kernel<<<MROWS * DM / 8 / 256, 256, 0, stream>>>(inputs, inA);
    tcast_kernel<<<dim3(DI / 64, DM / 64), 256, 0, stream>>>(Wz, WzT, DM, DI);
    tcast_kernel<<<dim3(CONVD / 64, DM / 64), 256, 0, stream>>>(Wxbc, WxbcT, DM, CONVD);
    tcast_kernel<<<dim3(DM / 64, DI / 64), 256, 0, stream>>>(Wout, WoutT, DI, DM);
    // 2. zxbc = inA @ [Wz | Wxbc]   (N = 4224; 1D grid = 128 M-tiles * 33 N-tiles)
    mfma_gemm<bf16><<<128 * (ZXW / 128), 256, 0, stream>>>(
        inA, WzT, zxbc, ZXW, DM, DM, ZXW);
    // 3. dt
    dt_kernel<<<MROWS * NH / 256, 256, 0, stream>>>(inputs, Wdt, dt_bias, dtb);
    // 4. conv x-part -> xdtT (transposed);  b/c part -> bmat/cmat
    conv_x<<<BB * 64 * 32, 256, 0, stream>>>(zxbc, conv_kernel, dtb, xdtT);
    conv_bc<<<MROWS * 128 / 8 / 256, 256, 0, stream>>>(zxbc, conv_kernel, bmat, cmat);
    // 5. cumsum
    cumsum_kernel<<<2, 256, 0, stream>>>(dtb, a_log, cumA, csum);
    // 6. per-chunk states (MFMA) -> st (bf16, over dead inA)
    states_mfma<<<BB * NC * NH, 256, 0, stream>>>(bmat, xdtT, cumA, csum, st);
    // 7. chunk scan (in place)
    scan_kernel<<<BB * NH * HD * DS / 256, 256, 0, stream>>>(st, csum);
    // 8. fused SSD y (MFMA) -> y cols of zxbc (xbc dead after conv)
    ssd_y_mfma<<<BB * NC * NH * 4, 256, 0, stream>>>(
        bmat, cmat, xdtT, st, cumA, zxbc + DI, ZXW);
    // 9. gate + rmsnorm (ynorm in place over y)
    gatenorm_kernel<<<MROWS, 256, 0, stream>>>(zxbc, gamma, zxbc);
    // 10. out = ynorm @ Wout   (1D grid = 128 M-tiles * 4 N-tiles)
    mfma_gemm<float><<<128 * (DM / 128), 256, 0, stream>>>(
        zxbc + DI, WoutT, out, DM, DI, ZXW, DM);
}

// Round 8
// 366.504 us; speedup vs baseline: 15.6868x; 1.0170x over previous
//
#include <hip/hip_runtime.h>
#include <hip/hip_bf16.h>

// Mamba2 block forward. B=4 L=4096 D_MODEL=512 D_INNER=2048 H=8 P=256 N=64
// CHUNK=256 C=16 CONV_DIM=2176.
// Round 8: mfma_gemm -> 2-phase double-buffered pipeline with counted
// s_waitcnt vmcnt(8) + raw s_barrier (T3/T4 minimum recipe): next tile's
// global_load_lds stays in flight across the barrier instead of the implicit
// vmcnt(0) drain. Everything else unchanged from round 7.

#define BB 4
#define LL 4096
#define DM 512
#define DI 2048
#define NH 8
#define HD 256
#define DS 64
#define DCONV 4
#define CHK 256
#define NC 16
#define CONVD 2176
#define MROWS (BB*LL)   // 16384
#define ZXW (DI + CONVD) // 4224

typedef __hip_bfloat16 bf16;
typedef short s8 __attribute__((ext_vector_type(8)));   // 8 bf16 (4 VGPRs)
typedef float f4 __attribute__((ext_vector_type(4)));   // MFMA acc

__device__ __forceinline__ f4 mfma16(s8 a, s8 b, f4 c) {
    return __builtin_amdgcn_mfma_f32_16x16x32_bf16(a, b, c, 0, 0, 0);
}

__device__ __forceinline__ void gload16(const bf16* g, bf16* l) {
    __builtin_amdgcn_global_load_lds(
        (const __attribute__((address_space(1))) void*)g,
        (__attribute__((address_space(3))) void*)l, 16, 0, 0);
}

__device__ __forceinline__ float ldf(const float* p) { return *p; }
__device__ __forceinline__ float ldf(const bf16* p) { return __bfloat162float(*p); }
__device__ __forceinline__ void stf(float* p, float v) { *p = v; }
__device__ __forceinline__ void stf(bf16* p, float v) { *p = __float2bfloat16(v); }

// ---------------- f32 -> bf16 cast (8/thread) ----------------
__global__ void cast_bf16_kernel(const float* __restrict__ in, bf16* __restrict__ out) {
    long i8 = ((long)blockIdx.x * 256 + threadIdx.x) * 8;
    float4 a = *(const float4*)&in[i8];
    float4 b = *(const float4*)&in[i8 + 4];
    bf16 v[8];
    v[0] = __float2bfloat16(a.x); v[1] = __float2bfloat16(a.y);
    v[2] = __float2bfloat16(a.z); v[3] = __float2bfloat16(a.w);
    v[4] = __float2bfloat16(b.x); v[5] = __float2bfloat16(b.y);
    v[6] = __float2bfloat16(b.z); v[7] = __float2bfloat16(b.w);
    *(uint4*)&out[i8] = *(uint4*)v;
}

// ---------------- f32 [K][N] -> bf16 [N][K] transpose-cast (weights) ----------------
__global__ void tcast_kernel(const float* __restrict__ in, bf16* __restrict__ out,
                             int K, int N) {
    __shared__ float tile[64][65];
    int t = threadIdx.x;
    int n0 = blockIdx.x * 64, k0 = blockIdx.y * 64;
#pragma unroll
    for (int i = 0; i < 16; i++) {
        int u = t + i * 256; int kr = u >> 6, nc = u & 63;
        tile[kr][nc] = in[(long)(k0 + kr) * N + n0 + nc];
    }
    __syncthreads();
#pragma unroll
    for (int i = 0; i < 16; i++) {
        int u = t + i * 256; int nr = u >> 6, kc = u & 63;
        out[(long)(n0 + nr) * K + k0 + kc] = __float2bfloat16(tile[kc][nr]);
    }
}

// ---------------- bf16 MFMA GEMM: C[M][N] = A[M][K] @ BT[N][K]^T ----------------
// 128x128 tile, BK=64, 4 waves, 2-phase dbuf + counted vmcnt.
// 1D grid = 128 * nNt blocks (M-tiles MUST be 128). XCD-banded swizzle.
template <typename TC>
__global__ __launch_bounds__(256) void mfma_gemm(const bf16* __restrict__ A,
                                                 const bf16* __restrict__ BT,
                                                 TC* __restrict__ C, int N, int K,
                                                 int lda, int ldc) {
    __shared__ __align__(16) char smem[65536];   // At[2]|Bt[2] staging; Ct epilogue alias
    bf16 (*At)[128][64] = (bf16(*)[128][64])smem;
    bf16 (*Bt)[128][64] = (bf16(*)[128][64])(smem + 32768);
    const int t = threadIdx.x, lane = t & 63, w = t >> 6;
    const int wr = w >> 1, wc = w & 1;
    const int bid = blockIdx.x;
    const int idx = bid >> 3;
    const int mt = (bid & 7) * 16 + (idx & 15);   // nMt = 128 fixed
    const int nt = idx >> 4;
    const long m0 = (long)mt * 128;
    const int n0 = nt * 128;
    const int lrow = lane >> 3, lblk = lane & 7;
    const int KT = K >> 6;
    f4 acc[4][4];
#pragma unroll
    for (int mi = 0; mi < 4; mi++)
#pragma unroll
        for (int ni = 0; ni < 4; ni++) acc[mi][ni] = (f4){0.f, 0.f, 0.f, 0.f};

    // stage tile kt into buffer bu: 8 gload16 per wave (wave-uniform LDS base)
    auto STAGE = [&](int bu, int kt) {
        int k0 = kt << 6;
#pragma unroll
        for (int i = 0; i < 4; i++) {
            int rbase = w * 32 + i * 8;
            int row = rbase + lrow;
            int kb = (lblk ^ (row & 7)) << 3;   // source k-block, pre-swizzled
            gload16(&A[(m0 + row) * (long)lda + k0 + kb], &At[bu][rbase][0]);
            gload16(&BT[((long)n0 + row) * K + k0 + kb], &Bt[bu][rbase][0]);
        }
    };

    STAGE(0, 0);
    int bu = 0;
    for (int kt = 0; kt < KT; kt++) {
        if (kt + 1 < KT) {
            STAGE(bu ^ 1, kt + 1);                    // prefetch: 8 more in flight
            asm volatile("s_waitcnt vmcnt(8)" ::: "memory");  // current tile landed
        } else {
            asm volatile("s_waitcnt vmcnt(0)" ::: "memory");
        }
        __builtin_amdgcn_sched_barrier(0);
        __builtin_amdgcn_s_barrier();
        __builtin_amdgcn_s_setprio(1);
#pragma unroll
        for (int ks = 0; ks < 2; ks++) {
            int k8 = ks * 4 + (lane >> 4);
            s8 af[4], bfr[4];
#pragma unroll
            for (int mi = 0; mi < 4; mi++) {
                int row = wr * 64 + mi * 16 + (lane & 15);
                af[mi] = *(const s8*)&At[bu][row][(k8 ^ (row & 7)) << 3];
            }
#pragma unroll
            for (int ni = 0; ni < 4; ni++) {
                int row = wc * 64 + ni * 16 + (lane & 15);
                bfr[ni] = *(const s8*)&Bt[bu][row][(k8 ^ (row & 7)) << 3];
            }
#pragma unroll
            for (int mi = 0; mi < 4; mi++)
#pragma unroll
                for (int ni = 0; ni < 4; ni++)
                    acc[mi][ni] = mfma16(af[mi], bfr[ni], acc[mi][ni]);
        }
        __builtin_amdgcn_s_setprio(0);
        __builtin_amdgcn_s_barrier();   // all reads of buf[bu] done before re-stage
        bu ^= 1;
    }
    __syncthreads();
    if constexpr (sizeof(TC) == 2) {
        // LDS-staged coalesced writeback (rows 272B, 16B-aligned)
        bf16 (*Ct)[136] = (bf16(*)[136])smem;
#pragma unroll
        for (int mi = 0; mi < 4; mi++)
#pragma unroll
            for (int ni = 0; ni < 4; ni++)
#pragma unroll
                for (int r = 0; r < 4; r++)
                    Ct[wr * 64 + mi * 16 + (lane >> 4) * 4 + r]
                      [wc * 64 + ni * 16 + (lane & 15)] =
                        __float2bfloat16(acc[mi][ni][r]);
        __syncthreads();
#pragma unroll
        for (int i = 0; i < 8; i++) {
            int u = t + i * 256; int row = u >> 4, j = u & 15;
            *(uint4*)&C[(m0 + row) * (long)ldc + n0 + j * 8] = *(uint4*)&Ct[row][j * 8];
        }
    } else {
#pragma unroll
        for (int mi = 0; mi < 4; mi++)
#pragma unroll
            for (int ni = 0; ni < 4; ni++)
#pragma unroll
                for (int r = 0; r < 4; r++)
                    stf(&C[(m0 + wr * 64 + mi * 16 + (lane >> 4) * 4 + r) * (long)ldc +
                           n0 + wc * 64 + ni * 16 + (lane & 15)], acc[mi][ni][r]);
    }
}

// ---------------- dt = softplus(inputs @ Wdt + bias) ----------------
__global__ void dt_kernel(const float* __restrict__ inp, const float* __restrict__ Wdt,
                          const float* __restrict__ dt_bias, float* __restrict__ dtb) {
    __shared__ float wlds[DM * NH];  // 16 KB
    int t = threadIdx.x;
#pragma unroll
    for (int i = 0; i < 16; i++) wlds[t + i * 256] = Wdt[t + i * 256];
    __syncthreads();
    int idx = blockIdx.x * 256 + t;
    int h = idx & 7;
    long row = idx >> 3;
    const float* ir = inp + row * DM;
    float acc = 0.f;
    for (int k = 0; k < DM; k += 4) {
        float4 a = *(const float4*)&ir[k];
        acc += a.x * wlds[k * 8 + h] + a.y * wlds[(k + 1) * 8 + h]
             + a.z * wlds[(k + 2) * 8 + h] + a.w * wlds[(k + 3) * 8 + h];
    }
    acc += dt_bias[h];
    float sp = acc > 20.f ? acc : log1pf(expf(acc));
    dtb[idx] = sp;
}

// ---------------- conv_x: conv(4)+silu+*dt over x channels, writes xdtT ----------------
__global__ __launch_bounds__(256) void conv_x(const bf16* __restrict__ zxbc,
                                              const float* __restrict__ ck,
                                              const float* __restrict__ dtb,
                                              bf16* __restrict__ xdtT) {
    __shared__ __align__(16) bf16 in_lds[67][72];
    __shared__ __align__(16) bf16 out_lds[64][64];
    __shared__ float dts[64];
    const int bid = blockIdx.x;
    const int ct = bid & 31, lt = (bid >> 5) & 63, b = bid >> 11;
    const int t = threadIdx.x;
    const int l0 = lt * 64;
    const long brow = (long)b * LL;
    const int h = ct >> 2;

#pragma unroll
    for (int i = 0; i < 3; i++) {
        int u = t + i * 256;
        if (u < 536) {
            int r = u >> 3, c8 = (u & 7) * 8;
            int gl = l0 - 3 + r;
            uint4 v = (gl >= 0)
                ? *(const uint4*)&zxbc[(brow + gl) * ZXW + DI + ct * 64 + c8]
                : (uint4){0, 0, 0, 0};
            *(uint4*)&in_lds[r][c8] = v;
        }
    }
    if (t < 64) dts[t] = dtb[(brow + l0 + t) * NH + h];
    __syncthreads();

    const int ch = t & 63, w = t >> 6;
    const int gch = ct * 64 + ch;
    float k0 = ck[0 * CONVD + gch], k1 = ck[1 * CONVD + gch];
    float k2 = ck[2 * CONVD + gch], k3 = ck[3 * CONVD + gch];
    float w0 = __bfloat162float(in_lds[w * 16 + 0][ch]);
    float w1 = __bfloat162float(in_lds[w * 16 + 1][ch]);
    float w2 = __bfloat162float(in_lds[w * 16 + 2][ch]);
    bf16 o[16];
#pragma unroll
    for (int i = 0; i < 16; i++) {
        float w3 = __bfloat162float(in_lds[w * 16 + i + 3][ch]);
        float v = w0 * k0 + w1 * k1 + w2 * k2 + w3 * k3;
        float s = v / (1.f + __expf(-v));
        o[i] = __float2bfloat16(s * dts[w * 16 + i]);
        w0 = w1; w1 = w2; w2 = w3;
    }
#pragma unroll
    for (int j = 0; j < 2; j++) {
        int blk = w * 2 + j;
        *(uint4*)&out_lds[ch][((blk ^ (ch & 7)) << 3)] = *(uint4*)&o[j * 8];
    }
    __syncthreads();
#pragma unroll
    for (int i = 0; i < 2; i++) {
        int u = t + i * 256;
        int chr = u >> 3, l8 = u & 7;
        uint4 v = *(const uint4*)&out_lds[chr][((l8 ^ (chr & 7)) << 3)];
        *(uint4*)&xdtT[((long)b * DI + ct * 64 + chr) * LL + l0 + l8 * 8] = v;
    }
}

// ---------------- conv_bc: conv+silu for b/c channels ----------------
__global__ void conv_bc(const bf16* __restrict__ zxbc, const float* __restrict__ ck,
                        bf16* __restrict__ bm, bf16* __restrict__ cm) {
    long idx = (long)blockIdx.x * 256 + threadIdx.x;
    if (idx >= (long)MROWS * 128 / 8) return;
    long e0 = idx * 8;
    int ch = (int)(e0 & 127);
    long bl = e0 >> 7;
    int l = (int)(bl & (LL - 1));
    float acc[8] = {};
#pragma unroll
    for (int k = 0; k < DCONV; k++) {
        int ls = l - 3 + k;
        if (ls >= 0) {
            bf16 v[8];
            *(uint4*)v = *(const uint4*)&zxbc[(bl - l + ls) * ZXW + 2 * DI + ch];
            float4 c0 = *(const float4*)&ck[k * CONVD + DI + ch];
            float4 c1 = *(const float4*)&ck[k * CONVD + DI + ch + 4];
            acc[0] += __bfloat162float(v[0]) * c0.x;
            acc[1] += __bfloat162float(v[1]) * c0.y;
            acc[2] += __bfloat162float(v[2]) * c0.z;
            acc[3] += __bfloat162float(v[3]) * c0.w;
            acc[4] += __bfloat162float(v[4]) * c1.x;
            acc[5] += __bfloat162float(v[5]) * c1.y;
            acc[6] += __bfloat162float(v[6]) * c1.z;
            acc[7] += __bfloat162float(v[7]) * c1.w;
        }
    }
    bf16 o[8];
#pragma unroll
    for (int j = 0; j < 8; j++) {
        float s = acc[j] / (1.f + __expf(-acc[j]));
        o[j] = __float2bfloat16(s);
    }
    if (ch < DS) *(uint4*)&bm[bl * DS + ch] = *(uint4*)o;
    else         *(uint4*)&cm[bl * DS + (ch - DS)] = *(uint4*)o;
}

// ---------------- per-(b,h,c) cumsum of a*dt ----------------
__global__ void cumsum_kernel(const float* __restrict__ dtb, const float* __restrict__ a_log,
                              float* __restrict__ cumA, float* __restrict__ csum) {
    int t = blockIdx.x * 256 + threadIdx.x;  // t = b*128 + h*16 + c
    if (t >= BB * NH * NC) return;
    int c = t & 15, h = (t >> 4) & 7, b = t >> 7;
    float a = -expf(a_log[h]);
    long base_l = (long)b * LL + (long)c * CHK;
    float s = 0.f;
    long obase = (long)t * CHK;
    for (int i = 0; i < CHK; i++) {
        s += a * dtb[(base_l + i) * NH + h];
        cumA[obase + i] = s;
    }
    csum[t] = s;
}

// ---------------- states via MFMA: st[p][n] = sum_l x[l,p]*b[l,n]*dec[l] ----------------
__global__ __launch_bounds__(256) void states_mfma(
        const bf16* __restrict__ bmat, const bf16* __restrict__ xdtT,
        const float* __restrict__ cumA, const float* __restrict__ csum,
        bf16* __restrict__ st) {
    __shared__ __align__(16) bf16 XT[256][72];
    __shared__ __align__(16) bf16 BT[64][72];
    const int z = blockIdx.x;  // b*128 + c*8 + h
    const int h = z & 7, c = (z >> 3) & 15, b = z >> 7;
    const long blr = (long)b * LL + (long)c * CHK;
    const int bhc = (b * NH + h) * NC + c;
    const float A = csum[bhc];
    const int t = threadIdx.x, lane = t & 63, w = t >> 6;
    const bf16* xrow = xdtT + ((long)b * DI + h * HD) * LL + c * CHK;
    f4 acc[4][4];
#pragma unroll
    for (int mi = 0; mi < 4; mi++)
#pragma unroll
        for (int ni = 0; ni < 4; ni++) acc[mi][ni] = (f4){0.f, 0.f, 0.f, 0.f};

    for (int lt = 0; lt < 4; lt++) {
        const int l0 = lt * 64;
#pragma unroll
        for (int i = 0; i < 2; i++) {
            int u = t + i * 256; int l = u >> 3, n8 = (u & 7) * 8;
            bf16 v[8];
            *(uint4*)v = *(const uint4*)&bmat[(blr + l0 + l) * DS + n8];
            float d = __expf(A - cumA[(long)bhc * CHK + l0 + l]);
#pragma unroll
            for (int j = 0; j < 8; j++) {
                int n = n8 + j;
                BT[n][l ^ ((n & 7) << 3)] = __float2bfloat16(__bfloat162float(v[j]) * d);
            }
        }
#pragma unroll
        for (int i = 0; i < 8; i++) {
            int u = t + i * 256; int pp = u >> 3, s8 = u & 7;
            *(uint4*)&XT[pp][s8 * 8] =
                *(const uint4*)&xrow[(long)pp * LL + l0 + ((s8 ^ (pp & 7)) << 3)];
        }
        __syncthreads();
        __builtin_amdgcn_s_setprio(1);
#pragma unroll
        for (int ks = 0; ks < 2; ks++) {
            int col = ks * 32 + (lane >> 4) * 8;
            s8 af[4], bx[4];
#pragma unroll
            for (int mi = 0; mi < 4; mi++) {
                int n = mi * 16 + (lane & 15);
                af[mi] = *(const s8*)&BT[n][col ^ ((n & 7) << 3)];
            }
#pragma unroll
            for (int ni = 0; ni < 4; ni++) {
                int p = w * 64 + ni * 16 + (lane & 15);
                bx[ni] = *(const s8*)&XT[p][col ^ ((p & 7) << 3)];
            }
#pragma unroll
            for (int mi = 0; mi < 4; mi++)
#pragma unroll
                for (int ni = 0; ni < 4; ni++)
                    acc[mi][ni] = mfma16(af[mi], bx[ni], acc[mi][ni]);
        }
        __builtin_amdgcn_s_setprio(0);
        __syncthreads();
    }
    bf16* so = st + (long)z * (HD * DS);
#pragma unroll
    for (int mi = 0; mi < 4; mi++)
#pragma unroll
        for (int ni = 0; ni < 4; ni++) {
            int p = w * 64 + ni * 16 + (lane & 15);
            int n0 = mi * 16 + (lane >> 4) * 4;
            bf16 vv[4];
#pragma unroll
            for (int r = 0; r < 4; r++) vv[r] = __float2bfloat16(acc[mi][ni][r]);
            *(uint2*)&so[p * 64 + n0] = *(uint2*)vv;
        }
}

// ---------------- serial chunk scan (in place, bf16, f32 accum in regs) ----------------
__global__ void scan_kernel(bf16* __restrict__ st, const float* __restrict__ csum) {
    long idx = (long)blockIdx.x * 256 + threadIdx.x;
    int pn = (int)(idx & 16383);
    int h = (int)((idx >> 14) & 7);
    int b = (int)(idx >> 17);
    float S = 0.f;
    for (int c = 0; c < NC; c++) {
        long si = (((long)(b * NC + c) * NH + h) * (HD * DS)) + pn;
        float chunk = __bfloat162float(st[si]);
        st[si] = __float2bfloat16(S);
        S = S * __expf(csum[(b * NH + h) * NC + c]) + chunk;
    }
}

// ---------------- fused SSD y via MFMA (uniform XOR-swizzle convention) ----------------
__global__ __launch_bounds__(256) void ssd_y_mfma(
        const bf16* __restrict__ bmat, const bf16* __restrict__ cmat,
        const bf16* __restrict__ xdtT, const bf16* __restrict__ st,
        const float* __restrict__ cumA, bf16* __restrict__ y, int ldy) {
    __shared__ __align__(16) bf16 cT[64][64];
    __shared__ __align__(16) bf16 bW[64][64];
    __shared__ __align__(16) bf16 XTt[256][64];
    __shared__ float cumL[64], cumS[64];

    const int t = threadIdx.x, lane = t & 63, w = t >> 6;
    const int bid0 = blockIdx.x;
    const int bid = (bid0 & 7) * 256 + (bid0 >> 3);   // XCD swizzle, grid=2048
    const int zt = bid >> 2, lt = bid & 3;
    const int h = zt & 7, c = (zt >> 3) & 15, b = zt >> 7;
    const long blr = (long)b * LL + (long)c * CHK;
    const int bhc = (b * NH + h) * NC + c;
    const int l0 = lt * 64;
    const bf16* xrow = xdtT + ((long)b * DI + h * HD) * LL + c * CHK;

#pragma unroll
    for (int i = 0; i < 2; i++) {
        int u = t + i * 256; int row = u >> 3, pb = u & 7;
        *(uint4*)&cT[row][pb * 8] =
            *(const uint4*)&cmat[(blr + l0 + row) * DS + ((pb ^ (row & 7)) << 3)];
    }
    if (t < 64) cumL[t] = cumA[(long)bhc * CHK + l0 + t];

    f4 acc[4][4];
#pragma unroll
    for (int mi = 0; mi < 4; mi++)
#pragma unroll
        for (int ni = 0; ni < 4; ni++) acc[mi][ni] = (f4){0.f, 0.f, 0.f, 0.f};
    __syncthreads();

    for (int stile = 0; stile <= lt; stile++) {
        const int s0 = stile * 64;
#pragma unroll
        for (int i = 0; i < 2; i++) {
            int u = t + i * 256; int row = u >> 3, pb = u & 7;
            *(uint4*)&bW[row][pb * 8] =
                *(const uint4*)&bmat[(blr + s0 + row) * DS + ((pb ^ (row & 7)) << 3)];
        }
        if (t < 64) cumS[t] = cumA[(long)bhc * CHK + s0 + t];
#pragma unroll
        for (int i = 0; i < 8; i++) {
            int u = t + i * 256; int pp = u >> 3, pb = u & 7;
            *(uint4*)&XTt[pp][pb * 8] =
                *(const uint4*)&xrow[(long)pp * LL + s0 + ((pb ^ (pp & 7)) << 3)];
        }
        __syncthreads();

        f4 wacc[4];
#pragma unroll
        for (int ni = 0; ni < 4; ni++) wacc[ni] = (f4){0.f, 0.f, 0.f, 0.f};
        __builtin_amdgcn_s_setprio(1);
#pragma unroll
        for (int ks = 0; ks < 2; ks++) {
            int kb = ks * 4 + (lane >> 4);
            int arow = w * 16 + (lane & 15);
            s8 af = *(const s8*)&cT[arow][(kb ^ (arow & 7)) << 3];
#pragma unroll
            for (int ni = 0; ni < 4; ni++) {
                int brow = ni * 16 + (lane & 15);
                s8 bfr = *(const s8*)&bW[brow][(kb ^ (brow & 7)) << 3];
                wacc[ni] = mfma16(af, bfr, wacc[ni]);
            }
        }
        __builtin_amdgcn_s_setprio(0);
        __syncthreads();

#pragma unroll
        for (int ni = 0; ni < 4; ni++) {
            int s_idx = ni * 16 + (lane & 15);
#pragma unroll
            for (int r = 0; r < 4; r++) {
                int l_loc = w * 16 + (lane >> 4) * 4 + r;
                bool valid = (stile < lt) || (l_loc >= s_idx);
                float val = valid ? wacc[ni][r] * __expf(cumL[l_loc] - cumS[s_idx]) : 0.f;
                bW[l_loc][(((s_idx >> 3) ^ (l_loc & 7)) << 3) + (s_idx & 7)] =
                    __float2bfloat16(val);
            }
        }
        __syncthreads();

        __builtin_amdgcn_s_setprio(1);
#pragma unroll
        for (int ks = 0; ks < 2; ks++) {
            int kb = ks * 4 + (lane >> 4);
            s8 aw[4], bx[4];
#pragma unroll
            for (int mi = 0; mi < 4; mi++) {
                int arow = mi * 16 + (lane & 15);
                aw[mi] = *(const s8*)&bW[arow][(kb ^ (arow & 7)) << 3];
            }
#pragma unroll
            for (int ni = 0; ni < 4; ni++) {
                int p = w * 64 + ni * 16 + (lane & 15);
                bx[ni] = *(const s8*)&XTt[p][(kb ^ (p & 7)) << 3];
            }
#pragma unroll
            for (int mi = 0; mi < 4; mi++)
#pragma unroll
                for (int ni = 0; ni < 4; ni++)
                    acc[mi][ni] = mfma16(aw[mi], bx[ni], acc[mi][ni]);
        }
        __builtin_amdgcn_s_setprio(0);
        __syncthreads();
    }

#pragma unroll
    for (int i = 0; i < 16; i++) {
        int u = t + i * 256; int l = u >> 6, n = u & 63;
        int pc = (((n >> 3) ^ (l & 7)) << 3) + (n & 7);
        bW[l][pc] = __float2bfloat16(__bfloat162float(cT[l][pc]) * __expf(cumL[l]));
    }
    {
        const bf16* sp = st + (long)zt * (HD * DS) + t * DS;
#pragma unroll
        for (int g = 0; g < 8; g++)
            *(uint4*)&XTt[t][g * 8] = *(const uint4*)&sp[(g ^ (t & 7)) << 3];
    }
    __syncthreads();
    __builtin_amdgcn_s_setprio(1);
#pragma unroll
    for (int ks = 0; ks < 2; ks++) {
        int kb = ks * 4 + (lane >> 4);
        s8 aw[4], bx[4];
#pragma unroll
        for (int mi = 0; mi < 4; mi++) {
            int arow = mi * 16 + (lane & 15);
            aw[mi] = *(const s8*)&bW[arow][(kb ^ (arow & 7)) << 3];
        }
#pragma unroll
        for (int ni = 0; ni < 4; ni++) {
            int p = w * 64 + ni * 16 + (lane & 15);
            bx[ni] = *(const s8*)&XTt[p][(kb ^ (p & 7)) << 3];
        }
#pragma unroll
        for (int mi = 0; mi < 4; mi++)
#pragma unroll
            for (int ni = 0; ni < 4; ni++)
                acc[mi][ni] = mfma16(aw[mi], bx[ni], acc[mi][ni]);
    }
    __builtin_amdgcn_s_setprio(0);
    __syncthreads();

    bf16* Yl = (bf16*)XTt;   // [64][256]
#pragma unroll
    for (int mi = 0; mi < 4; mi++)
#pragma unroll
        for (int ni = 0; ni < 4; ni++)
#pragma unroll
            for (int r = 0; r < 4; r++)
                Yl[(mi * 16 + (lane >> 4) * 4 + r) * 256 + w * 64 + ni * 16 + (lane & 15)] =
                    __float2bfloat16(acc[mi][ni][r]);
    __syncthreads();
#pragma unroll
    for (int i = 0; i < 8; i++) {
        int u = t + i * 256; int l = u >> 5, p8 = u & 31;
        *(uint4*)&y[(blr + l0 + l) * (long)ldy + h * HD + p8 * 8] =
            *(uint4*)&Yl[l * 256 + p8 * 8];
    }
}

// ---------------- gate (silu(z)) + RMSNorm, strided over zxbc ----------------
__global__ void gatenorm_kernel(const bf16* __restrict__ zxbc,
                                const float* __restrict__ gamma, bf16* __restrict__ out) {
    int row = blockIdx.x;
    int tid = threadIdx.x;
    int d0 = tid * 8;
    bf16 yv[8], zv[8];
    *(uint4*)yv = *(const uint4*)&zxbc[(long)row * ZXW + DI + d0];  // y (over xbc cols)
    *(uint4*)zv = *(const uint4*)&zxbc[(long)row * ZXW + d0];       // z
    float g[8];
    float ss = 0.f;
#pragma unroll
    for (int i = 0; i < 8; i++) {
        float zf = __bfloat162float(zv[i]);
        float gate = zf / (1.f + __expf(-zf));
        float v = __bfloat162float(yv[i]) * gate;
        g[i] = v;
        ss += v * v;
    }
#pragma unroll
    for (int off = 32; off > 0; off >>= 1) ss += __shfl_down(ss, off);
    __shared__ float red[4];
    if ((tid & 63) == 0) red[tid >> 6] = ss;
    __syncthreads();
    float tot = red[0] + red[1] + red[2] + red[3];
    float scale = rsqrtf(tot / (float)DI + 1e-5f);
    float4 g0 = *(const float4*)&gamma[d0];
    float4 g1 = *(const float4*)&gamma[d0 + 4];
    bf16 o[8];
    o[0] = __float2bfloat16(g[0] * scale * g0.x);
    o[1] = __float2bfloat16(g[1] * scale * g0.y);
    o[2] = __float2bfloat16(g[2] * scale * g0.z);
    o[3] = __float2bfloat16(g[3] * scale * g0.w);
    o[4] = __float2bfloat16(g[4] * scale * g1.x);
    o[5] = __float2bfloat16(g[5] * scale * g1.y);
    o[6] = __float2bfloat16(g[6] * scale * g1.z);
    o[7] = __float2bfloat16(g[7] * scale * g1.w);
    *(uint4*)&out[(long)row * ZXW + DI + d0] = *(uint4*)o;  // ynorm in place
}

extern "C" void kernel_launch(void* const* d_in, const int* in_sizes, int n_in,
                              void* d_out, int out_size, void* d_ws, size_t ws_size,
                              hipStream_t stream) {
    const float* inputs = (const float*)d_in[0];
    const float* Wz = (const float*)d_in[1];
    const float* Wxbc = (const float*)d_in[2];
    const float* Wdt = (const float*)d_in[3];
    const float* conv_kernel = (const float*)d_in[4];
    const float* dt_bias = (const float*)d_in[5];
    const float* a_log = (const float*)d_in[6];
    const float* gamma = (const float*)d_in[7];
    const float* Wout = (const float*)d_in[8];
    float* out = (float*)d_out;

    // ---- workspace layout (~223 MiB) ----
    char* p = (char*)d_ws;
    float* dtb = (float*)p;      p += (long)MROWS * NH * 4;
    float* cumA = (float*)p;     p += (long)MROWS * NH * 4;
    float* csum = (float*)p;     p += 512 * 4;
    bf16* WzT = (bf16*)p;        p += (long)DI * DM * 2;      // [WzT;WxbcT] adjacent
    bf16* WxbcT = (bf16*)p;      p += (long)CONVD * DM * 2;   //  = [4224][512]
    bf16* WoutT = (bf16*)p;      p += (long)DM * DI * 2;
    bf16* bmat = (bf16*)p;       p += (long)MROWS * DS * 2;
    bf16* cmat = (bf16*)p;       p += (long)MROWS * DS * 2;
    bf16* inA = (bf16*)p;        p += (long)MROWS * DM * 2;   // -> st (bf16) after GEMM
    bf16* zxbc = (bf16*)p;       p += (long)MROWS * ZXW * 2;  // z|xbc -> z|y -> z|ynorm
    bf16* xdtT = (bf16*)p;       p += (long)DI * BB * LL * 2; // 67 MB
    bf16* st = inA;

    // 1. casts / weight transposes
    cast_bf16_kernel<<<MROWS * DM / 8 / 256, 256, 0, stream>>>(inputs, inA);
    tcast_kernel<<<dim3(DI / 64, DM / 64), 256, 0, stream>>>(Wz, WzT, DM, DI);
    tcast_kernel<<<dim3(CONVD / 64, DM / 64), 256, 0, stream>>>(Wxbc, WxbcT, DM, CONVD);
    tcast_kernel<<<dim3(DM / 64, DI / 64), 256, 0, stream>>>(Wout, WoutT, DI, DM);
    // 2. zxbc = inA @ [Wz | Wxbc]   (N = 4224; 1D grid = 128 M-tiles * 33 N-tiles)
    mfma_gemm<bf16><<<128 * (ZXW / 128), 256, 0, stream>>>(
        inA, WzT, zxbc, ZXW, DM, DM, ZXW);
    // 3. dt
    dt_kernel<<<MROWS * NH / 256, 256, 0, stream>>>(inputs, Wdt, dt_bias, dtb);
    // 4. conv x-part -> xdtT (transposed);  b/c part -> bmat/cmat
    conv_x<<<BB * 64 * 32, 256, 0, stream>>>(zxbc, conv_kernel, dtb, xdtT);
    conv_bc<<<MROWS * 128 / 8 / 256, 256, 0, stream>>>(zxbc, conv_kernel, bmat, cmat);
    // 5. cumsum
    cumsum_kernel<<<2, 256, 0, stream>>>(dtb, a_log, cumA, csum);
    // 6. per-chunk states (MFMA) -> st (bf16, over dead inA)
    states_mfma<<<BB * NC * NH, 256, 0, stream>>>(bmat, xdtT, cumA, csum, st);
    // 7. chunk scan (in place)
    scan_kernel<<<BB * NH * HD * DS / 256, 256, 0, stream>>>(st, csum);
    // 8. fused SSD y (MFMA) -> y cols of zxbc (xbc dead after conv)
    ssd_y_mfma<<<BB * NC * NH * 4, 256, 0, stream>>>(
        bmat, cmat, xdtT, st, cumA, zxbc + DI, ZXW);
    // 9. gate + rmsnorm (ynorm in place over y)
    gatenorm_kernel<<<MROWS, 256, 0, stream>>>(zxbc, gamma, zxbc);
    // 10. out = ynorm @ Wout   (1D grid = 128 M-tiles * 4 N-tiles)
    mfma_gemm<float><<<128 * (DM / 128), 256, 0, stream>>>(
        zxbc + DI, WoutT, out, DM, DI, ZXW, DM);
}